// Round 8
// baseline (118.742 us; speedup 1.0000x reference)
//
#include <hip/hip_runtime.h>

typedef __bf16 bf16x8 __attribute__((ext_vector_type(8)));
typedef __bf16 bf16x4 __attribute__((ext_vector_type(4)));
typedef float f32x4 __attribute__((ext_vector_type(4)));

#define MFMA(a, b, c) __builtin_amdgcn_mfma_f32_16x16x32_bf16(a, b, c, 0, 0, 0)

#define CS 0.18033688011112042f   /* 0.125 * log2(e) */

__device__ __forceinline__ ushort f2bf(float f) {
    __bf16 h = (__bf16)f;
    return *(ushort*)&h;
}

// ---- stage an (8*nchunks)-row x 64-col bf16 tile into LDS, XOR-swizzled ----
// LDS dest linear (global_load_lds requirement); per-lane GLOBAL source address
// pre-swizzled (m173 pattern). One 1KB chunk (8 rows x 128B) per wave-instr.
__device__ __forceinline__ void stage_tile64(ushort* lds, const ushort* gbase,
                                             int row_stride, int nchunks,
                                             int wave, int lane) {
    int r8 = lane >> 3;                       // row within 8-row chunk
    int cswz = ((lane & 7) ^ r8) << 4;        // pre-swizzled source byte col
#pragma unroll
    for (int c = wave; c < nchunks; c += 4) {
        const char* g = (const char*)(gbase + (size_t)(c * 8 + r8) * row_stride) + cswz;
        __builtin_amdgcn_global_load_lds(
            (const __attribute__((address_space(1))) unsigned int*)g,
            (__attribute__((address_space(3))) unsigned int*)((char*)lds + c * 1024),
            16, 0, 0);
    }
}

// swizzled read of logical (row, col-byte cb), 16B
__device__ __forceinline__ bf16x8 lds_read_row(const ushort* lds, int row, int cb) {
    return *(const bf16x8*)((const char*)lds + row * 128 + (cb ^ ((row & 7) << 4)));
}

// ---------------------------------------------------------------- groupnorm (+fused weight cvt)
// blocks [0,256): GroupNorm per (b,g); blocks [256,1280): fp32->bf16 weight cvt
__global__ __launch_bounds__(256) void gn_cvt_kernel(const float* __restrict__ x,
                                                     const float* __restrict__ gnw,
                                                     const float* __restrict__ gnb,
                                                     ushort* __restrict__ hnT,
                                                     const float* __restrict__ w1,
                                                     const float* __restrict__ w2,
                                                     ushort* __restrict__ o1,
                                                     ushort* __restrict__ o2) {
    if (blockIdx.x >= 256) {
        int t = (blockIdx.x - 256) * 256 + threadIdx.x;
        const int n1q = (1536 * 512) / 4;
        float4 v;
        ushort* dst;
        int idx;
        if (t < n1q) {
            v = ((const float4*)w1)[t]; dst = o1; idx = t;
        } else {
            idx = t - n1q;
            v = ((const float4*)w2)[idx]; dst = o2;
        }
        ushort4 p;
        p.x = f2bf(v.x); p.y = f2bf(v.y); p.z = f2bf(v.z); p.w = f2bf(v.w);
        ((ushort4*)dst)[idx] = p;
        return;
    }

    int b = blockIdx.x >> 5, g = blockIdx.x & 31;
    const float* xp = x + (size_t)(b * 512 + g * 16) * 1024;
    int t = threadIdx.x;

    float s = 0.f, ss = 0.f;
    const float4* xp4 = (const float4*)xp;
    for (int i = t; i < 4096; i += 256) {
        float4 v = xp4[i];
        s += (v.x + v.y) + (v.z + v.w);
        ss += (v.x * v.x + v.y * v.y) + (v.z * v.z + v.w * v.w);
    }
#pragma unroll
    for (int off = 32; off >= 1; off >>= 1) {
        s += __shfl_xor(s, off);
        ss += __shfl_xor(ss, off);
    }
    __shared__ float red[8];
    __shared__ float sw[16], sb[16];
    int wave = t >> 6;
    if ((t & 63) == 0) { red[wave] = s; red[wave + 4] = ss; }
    if (t < 16) { sw[t] = gnw[g * 16 + t]; sb[t] = gnb[g * 16 + t]; }
    __syncthreads();
    float S = red[0] + red[1] + red[2] + red[3];
    float SS = red[4] + red[5] + red[6] + red[7];
    float mean = S * (1.0f / 16384.0f);
    float var = SS * (1.0f / 16384.0f) - mean * mean;
    float rstd = rsqrtf(var + 1e-5f);

    __shared__ ushort tile[16][258];
    int cc0 = (t & 3) * 4;
    int nb = t >> 2;
    for (int chunk = 0; chunk < 4; ++chunk) {
        __syncthreads();
#pragma unroll
        for (int cc = 0; cc < 16; ++cc) {
            float v = xp[cc * 1024 + chunk * 256 + t];
            tile[cc][t] = f2bf((v - mean) * rstd * sw[cc] + sb[cc]);
        }
        __syncthreads();
        size_t rowbase = (size_t)b * 1024 + chunk * 256;
#pragma unroll
        for (int k = 0; k < 4; ++k) {
            int nl = nb + 64 * k;
            ushort4 p;
            p.x = tile[cc0 + 0][nl];
            p.y = tile[cc0 + 1][nl];
            p.z = tile[cc0 + 2][nl];
            p.w = tile[cc0 + 3][nl];
            *(ushort4*)(hnT + (rowbase + nl) * 512 + g * 16 + cc0) = p;
        }
    }
}

// ---------------------------------------------------------------- QKV GEMM
// linear grid 768; XCD swizzle: b = i&7 (one batch per XCD -> hnT[b]+W L2-resident)
// Q outputs pre-scaled by CS so attention computes exp2(S) directly.
// V written with kv-axis permuted within each 64-token block:
//   n' = 4*(n&15) + ((n>>4)&3)  -- matches attention's packed-P layout.
__global__ __launch_bounds__(256) void gemm_qkv(const ushort* __restrict__ Wb,
                                                const ushort* __restrict__ hnT,
                                                const float* __restrict__ qkvb,
                                                ushort* __restrict__ qT,
                                                ushort* __restrict__ kT,
                                                ushort* __restrict__ vb) {
    int lane = threadIdx.x & 63, wave = threadIdx.x >> 6;
    int l15 = lane & 15, lg = lane >> 4;
    int bi = blockIdx.x;
    int b = bi & 7;
    int slot = bi >> 3;            // 0..95
    int m0 = (slot % 12) * 128;
    int n0 = (slot / 12) * 128;
    int mw = (wave >> 1) * 64, nw = (wave & 1) * 64;
    const ushort* bb = hnT + (size_t)b * 524288;

    __shared__ ushort abuf[2][8192];
    __shared__ ushort bbuf[2][8192];

    f32x4 acc[4][4] = {};
    stage_tile64(abuf[0], Wb + (size_t)m0 * 512, 512, 16, wave, lane);
    stage_tile64(bbuf[0], bb + (size_t)n0 * 512, 512, 16, wave, lane);
    __syncthreads();
    int cur = 0;
#pragma unroll 1
    for (int t = 0; t < 8; ++t) {
        if (t < 7) {
            stage_tile64(abuf[cur ^ 1], Wb + (size_t)m0 * 512 + (t + 1) * 64, 512, 16, wave, lane);
            stage_tile64(bbuf[cur ^ 1], bb + (size_t)n0 * 512 + (t + 1) * 64, 512, 16, wave, lane);
        }
#pragma unroll
        for (int kh = 0; kh < 2; kh++) {
            bf16x8 af[4], bfr[4];
#pragma unroll
            for (int i = 0; i < 4; i++)
                af[i] = lds_read_row(abuf[cur], mw + i * 16 + l15, kh * 64 + lg * 16);
#pragma unroll
            for (int j = 0; j < 4; j++)
                bfr[j] = lds_read_row(bbuf[cur], nw + j * 16 + l15, kh * 64 + lg * 16);
#pragma unroll
            for (int i = 0; i < 4; i++)
#pragma unroll
                for (int j = 0; j < 4; j++)
                    acc[i][j] = MFMA(af[i], bfr[j], acc[i][j]);
        }
        __syncthreads();
        cur ^= 1;
    }

#pragma unroll
    for (int i = 0; i < 4; i++) {
        int ob = m0 + mw + i * 16 + lg * 4;
        float bias[4];
#pragma unroll
        for (int r = 0; r < 4; r++) bias[r] = qkvb[ob + r];
        int part = ob >> 9;
        int oo = ob & 511;
#pragma unroll
        for (int j = 0; j < 4; j++) {
            int n = n0 + nw + j * 16 + l15;
            if (part == 2) {
                int np = (n & ~63) | (((n & 15) << 2) | ((n >> 4) & 3));
#pragma unroll
                for (int r = 0; r < 4; r++)
                    vb[(size_t)(b * 512 + oo + r) * 1024 + np] = f2bf(acc[i][j][r] + bias[r]);
            } else {
                ushort* dst = part ? kT : qT;
                float sc = part ? 1.0f : CS;      // pre-scale Q by 0.125*log2(e)
                int h = oo >> 6, dd = oo & 63;
                ushort4 p;
                p.x = f2bf((acc[i][j][0] + bias[0]) * sc);
                p.y = f2bf((acc[i][j][1] + bias[1]) * sc);
                p.z = f2bf((acc[i][j][2] + bias[2]) * sc);
                p.w = f2bf((acc[i][j][3] + bias[3]) * sc);
                *(ushort4*)(dst + ((size_t)((b * 8 + h) * 1024 + n)) * 64 + dd) = p;
            }
        }
    }
}

// ---------------------------------------------------------------- attention
// 128 q-rows/block (4 waves x 32 rows). K/V read DIRECTLY from global: per
// (b,h) K+V = 256KB is L2-resident after the XCD swizzle (all 8 q-blocks of a
// bh on one XCD), and the 4 waves of a block hit the same L1 lines (staging
// would be pure overhead -- m169 lesson). pbuf is per-wave private, so the
// main loop has NO __syncthreads: waves run decoupled and their MFMA / exp /
// load phases overlap naturally. V loads issued before the exp block so their
// latency hides under the 32 transcendentals.
// Q pre-scaled: P = exp2(S). Row sums via ones-MFMA. P packed (kv-permuted
// k' = 4*(kv&15)+(kv>>4), matching gemm_qkv's permuted V write).
__global__ __launch_bounds__(256) void attn_kernel(const ushort* __restrict__ qT,
                                                   const ushort* __restrict__ kT,
                                                   const ushort* __restrict__ vb,
                                                   ushort* __restrict__ aoT) {
    int bi = blockIdx.x;
    int bh = ((bi >> 6) << 3) | (bi & 7);
    int q0 = ((bi >> 3) & 7) * 128;
    int b = bh >> 3, h = bh & 7;
    int lane = threadIdx.x & 63, wave = threadIdx.x >> 6;
    int l15 = lane & 15, lg = lane >> 4;
    const ushort* qp = qT + (size_t)bh * 65536;
    const ushort* kp = kT + (size_t)bh * 65536;
    const ushort* vp = vb + (size_t)bh * 65536;

    __shared__ ushort pbuf[4][2048];   // per-wave [q 32][kv' 64]
    ushort* pw = pbuf[wave];

    bf16x8 vone;
#pragma unroll
    for (int e = 0; e < 8; e++) vone[e] = (__bf16)1.0f;

    bf16x8 qf[2][2];
#pragma unroll
    for (int i = 0; i < 2; i++)
#pragma unroll
        for (int kh = 0; kh < 2; kh++)
            qf[i][kh] = *(const bf16x8*)(qp + (size_t)(q0 + wave * 32 + i * 16 + l15) * 64 + kh * 32 + lg * 8);

    f32x4 oacc[2][4] = {};
    f32x4 lacc[2] = {};

#pragma unroll 1
    for (int t = 0; t < 16; ++t) {
        const ushort* kt = kp + t * 4096;

        // K fragments direct from global (L1/L2-served)
        bf16x8 kf[2][4];
#pragma unroll
        for (int kh = 0; kh < 2; kh++)
#pragma unroll
            for (int cf = 0; cf < 4; cf++)
                kf[kh][cf] = *(const bf16x8*)(kt + (size_t)(cf * 16 + l15) * 64 + kh * 32 + lg * 8);

        // V fragments direct from global, issued early (latency hides under exp)
        bf16x8 vf[2][4];
#pragma unroll
        for (int ks = 0; ks < 2; ks++)
#pragma unroll
            for (int cf = 0; cf < 4; cf++)
                vf[ks][cf] = *(const bf16x8*)(vp + (size_t)(cf * 16 + l15) * 1024 + t * 64 + ks * 32 + lg * 8);

        f32x4 sacc[2][4] = {};
        __builtin_amdgcn_s_setprio(1);
#pragma unroll
        for (int kh = 0; kh < 2; kh++)
#pragma unroll
            for (int cf = 0; cf < 4; cf++) {
                sacc[0][cf] = MFMA(qf[0][kh], kf[kh][cf], sacc[0][cf]);
                sacc[1][cf] = MFMA(qf[1][kh], kf[kh][cf], sacc[1][cf]);
            }
        __builtin_amdgcn_s_setprio(0);

        // P = exp2(S); pack 4 bf16 (cf=0..3, one row) -> one ds_write_b64
#pragma unroll
        for (int i = 0; i < 2; i++)
#pragma unroll
            for (int r = 0; r < 4; r++) {
                bf16x4 pq;
                pq[0] = (__bf16)exp2f(sacc[i][0][r]);
                pq[1] = (__bf16)exp2f(sacc[i][1][r]);
                pq[2] = (__bf16)exp2f(sacc[i][2][r]);
                pq[3] = (__bf16)exp2f(sacc[i][3][r]);
                int row = i * 16 + lg * 4 + r;
                *(bf16x4*)((char*)pw + row * 128 + ((l15 * 8) ^ ((row & 7) << 4))) = pq;
            }

        __builtin_amdgcn_s_setprio(1);
#pragma unroll
        for (int i = 0; i < 2; i++)
#pragma unroll
            for (int ks = 0; ks < 2; ks++) {
                bf16x8 pf = lds_read_row(pw, i * 16 + l15, ks * 64 + lg * 16);
                lacc[i] = MFMA(pf, vone, lacc[i]);   // row sums on matrix pipe
#pragma unroll
                for (int cf = 0; cf < 4; cf++)
                    oacc[i][cf] = MFMA(pf, vf[ks][cf], oacc[i][cf]);
            }
        __builtin_amdgcn_s_setprio(0);
    }

#pragma unroll
    for (int i = 0; i < 2; i++)
#pragma unroll
        for (int r = 0; r < 4; r++) {
            float inv = 1.0f / lacc[i][r];
            int n = q0 + wave * 32 + i * 16 + lg * 4 + r;
            size_t obase = ((size_t)b * 1024 + n) * 512 + h * 64;
#pragma unroll
            for (int cf = 0; cf < 4; cf++)
                aoT[obase + cf * 16 + l15] = f2bf(oacc[i][cf][r] * inv);
        }
}

// ---------------------------------------------------------------- proj GEMM + residual
// linear grid 512; XCD swizzle: b = i&7
__global__ __launch_bounds__(256) void gemm_proj(const ushort* __restrict__ Wb,
                                                 const ushort* __restrict__ aoT,
                                                 const float* __restrict__ projb,
                                                 const float* __restrict__ x,
                                                 float* __restrict__ out) {
    int lane = threadIdx.x & 63, wave = threadIdx.x >> 6;
    int l15 = lane & 15, lg = lane >> 4;
    int bi = blockIdx.x;
    int b = bi & 7;
    int slot = bi >> 3;            // 0..63
    int m0 = (slot & 3) * 128;
    int n0 = (slot >> 2) * 64;
    int mw = (wave >> 1) * 64, nw = (wave & 1) * 32;
    const ushort* bb = aoT + (size_t)b * 524288;

    __shared__ ushort abuf[2][8192];   // 128 x 64
    __shared__ ushort bbuf[2][4096];   // 64 x 64

    f32x4 acc[4][2] = {};
    stage_tile64(abuf[0], Wb + (size_t)m0 * 512, 512, 16, wave, lane);
    stage_tile64(bbuf[0], bb + (size_t)n0 * 512, 512, 8, wave, lane);
    __syncthreads();
    int cur = 0;
#pragma unroll 1
    for (int t = 0; t < 8; ++t) {
        if (t < 7) {
            stage_tile64(abuf[cur ^ 1], Wb + (size_t)m0 * 512 + (t + 1) * 64, 512, 16, wave, lane);
            stage_tile64(bbuf[cur ^ 1], bb + (size_t)n0 * 512 + (t + 1) * 64, 512, 8, wave, lane);
        }
#pragma unroll
        for (int kh = 0; kh < 2; kh++) {
            bf16x8 af[4], bfr[2];
#pragma unroll
            for (int i = 0; i < 4; i++)
                af[i] = lds_read_row(abuf[cur], mw + i * 16 + l15, kh * 64 + lg * 16);
#pragma unroll
            for (int j = 0; j < 2; j++)
                bfr[j] = lds_read_row(bbuf[cur], nw + j * 16 + l15, kh * 64 + lg * 16);
#pragma unroll
            for (int i = 0; i < 4; i++)
#pragma unroll
                for (int j = 0; j < 2; j++)
                    acc[i][j] = MFMA(af[i], bfr[j], acc[i][j]);
        }
        __syncthreads();
        cur ^= 1;
    }

#pragma unroll
    for (int i = 0; i < 4; i++) {
        int ob = m0 + mw + i * 16 + lg * 4;
        float bias[4];
#pragma unroll
        for (int r = 0; r < 4; r++) bias[r] = projb[ob + r];
#pragma unroll
        for (int j = 0; j < 2; j++) {
            int n = n0 + nw + j * 16 + l15;
#pragma unroll
            for (int r = 0; r < 4; r++) {
                size_t idx = (size_t)(b * 512 + ob + r) * 1024 + n;
                out[idx] = x[idx] + bias[r] + acc[i][j][r];
            }
        }
    }
}

// ---------------------------------------------------------------- launcher
extern "C" void kernel_launch(void* const* d_in, const int* in_sizes, int n_in,
                              void* d_out, int out_size, void* d_ws, size_t ws_size,
                              hipStream_t stream) {
    const float* x     = (const float*)d_in[0];
    const float* gnw   = (const float*)d_in[1];
    const float* gnb   = (const float*)d_in[2];
    const float* qkvw  = (const float*)d_in[3];
    const float* qkvb  = (const float*)d_in[4];
    const float* projw = (const float*)d_in[5];
    const float* projb = (const float*)d_in[6];
    float* out = (float*)d_out;

    char* ws = (char*)d_ws;
    ushort* hnT    = (ushort*)(ws);                          // 8 MB (reused as aoT)
    ushort* qT     = (ushort*)(ws + (size_t)(8u << 20));     // 8 MB
    ushort* kT     = (ushort*)(ws + (size_t)(16u << 20));    // 8 MB
    ushort* vbuf   = (ushort*)(ws + (size_t)(24u << 20));    // 8 MB
    ushort* qkvwb  = (ushort*)(ws + (size_t)(32u << 20));    // 1.5 MB
    ushort* projwb = (ushort*)(ws + (size_t)(32u << 20) + 1572864);  // 0.5 MB

    gn_cvt_kernel<<<dim3(1280), dim3(256), 0, stream>>>(x, gnw, gnb, hnT,
                                                        qkvw, projw, qkvwb, projwb);
    gemm_qkv<<<dim3(768), dim3(256), 0, stream>>>(qkvwb, hnT, qkvb, qT, kT, vbuf);
    attn_kernel<<<dim3(512), dim3(256), 0, stream>>>(qT, kT, vbuf, hnT /* aoT */);
    gemm_proj<<<dim3(512), dim3(256), 0, stream>>>(projwb, hnT, projb, x, out);
}

// Round 9
// 88.132 us; speedup vs baseline: 1.3473x; 1.3473x over previous
//
#include <hip/hip_runtime.h>

typedef __bf16 bf16x8 __attribute__((ext_vector_type(8)));
typedef float f32x4 __attribute__((ext_vector_type(4)));

#define MFMA(a, b, c) __builtin_amdgcn_mfma_f32_16x16x32_bf16(a, b, c, 0, 0, 0)

#define CS 0.18033688011112042f   /* 0.125 * log2(e) */

__device__ __forceinline__ ushort f2bf(float f) {
    __bf16 h = (__bf16)f;
    return *(ushort*)&h;
}

// ---- stage an (8*nchunks)-row x 64-col bf16 tile into LDS, XOR-swizzled ----
__device__ __forceinline__ void stage_tile64(ushort* lds, const ushort* gbase,
                                             int row_stride, int nchunks,
                                             int wave, int lane) {
    int r8 = lane >> 3;
    int cswz = ((lane & 7) ^ r8) << 4;
#pragma unroll
    for (int c = wave; c < nchunks; c += 4) {
        const char* g = (const char*)(gbase + (size_t)(c * 8 + r8) * row_stride) + cswz;
        __builtin_amdgcn_global_load_lds(
            (const __attribute__((address_space(1))) unsigned int*)g,
            (__attribute__((address_space(3))) unsigned int*)((char*)lds + c * 1024),
            16, 0, 0);
    }
}

__device__ __forceinline__ bf16x8 lds_read_row(const ushort* lds, int row, int cb) {
    return *(const bf16x8*)((const char*)lds + row * 128 + (cb ^ ((row & 7) << 4)));
}

// ---------------------------------------------------------------- groupnorm (+fused weight cvt)
__global__ __launch_bounds__(256) void gn_cvt_kernel(const float* __restrict__ x,
                                                     const float* __restrict__ gnw,
                                                     const float* __restrict__ gnb,
                                                     ushort* __restrict__ hnT,
                                                     const float* __restrict__ w1,
                                                     const float* __restrict__ w2,
                                                     ushort* __restrict__ o1,
                                                     ushort* __restrict__ o2) {
    if (blockIdx.x >= 256) {
        int t = (blockIdx.x - 256) * 256 + threadIdx.x;
        const int n1q = (1536 * 512) / 4;
        float4 v;
        ushort* dst;
        int idx;
        if (t < n1q) {
            v = ((const float4*)w1)[t]; dst = o1; idx = t;
        } else {
            idx = t - n1q;
            v = ((const float4*)w2)[idx]; dst = o2;
        }
        ushort4 p;
        p.x = f2bf(v.x); p.y = f2bf(v.y); p.z = f2bf(v.z); p.w = f2bf(v.w);
        ((ushort4*)dst)[idx] = p;
        return;
    }

    int b = blockIdx.x >> 5, g = blockIdx.x & 31;
    const float* xp = x + (size_t)(b * 512 + g * 16) * 1024;
    int t = threadIdx.x;

    float s = 0.f, ss = 0.f;
    const float4* xp4 = (const float4*)xp;
    for (int i = t; i < 4096; i += 256) {
        float4 v = xp4[i];
        s += (v.x + v.y) + (v.z + v.w);
        ss += (v.x * v.x + v.y * v.y) + (v.z * v.z + v.w * v.w);
    }
#pragma unroll
    for (int off = 32; off >= 1; off >>= 1) {
        s += __shfl_xor(s, off);
        ss += __shfl_xor(ss, off);
    }
    __shared__ float red[8];
    __shared__ float sw[16], sb[16];
    int wave = t >> 6;
    if ((t & 63) == 0) { red[wave] = s; red[wave + 4] = ss; }
    if (t < 16) { sw[t] = gnw[g * 16 + t]; sb[t] = gnb[g * 16 + t]; }
    __syncthreads();
    float S = red[0] + red[1] + red[2] + red[3];
    float SS = red[4] + red[5] + red[6] + red[7];
    float mean = S * (1.0f / 16384.0f);
    float var = SS * (1.0f / 16384.0f) - mean * mean;
    float rstd = rsqrtf(var + 1e-5f);

    __shared__ ushort tile[16][258];
    int cc0 = (t & 3) * 4;
    int nb = t >> 2;
    for (int chunk = 0; chunk < 4; ++chunk) {
        __syncthreads();
#pragma unroll
        for (int cc = 0; cc < 16; ++cc) {
            float v = xp[cc * 1024 + chunk * 256 + t];
            tile[cc][t] = f2bf((v - mean) * rstd * sw[cc] + sb[cc]);
        }
        __syncthreads();
        size_t rowbase = (size_t)b * 1024 + chunk * 256;
#pragma unroll
        for (int k = 0; k < 4; ++k) {
            int nl = nb + 64 * k;
            ushort4 p;
            p.x = tile[cc0 + 0][nl];
            p.y = tile[cc0 + 1][nl];
            p.z = tile[cc0 + 2][nl];
            p.w = tile[cc0 + 3][nl];
            *(ushort4*)(hnT + (rowbase + nl) * 512 + g * 16 + cc0) = p;
        }
    }
}

// ---------------------------------------------------------------- QKV GEMM
// V written with kv-axis permuted within each 64-token block by pi^-1 so that
// attention's in-register P fragments contract correctly:
//   L = n&63; cf=L>>4; s = (cf>>1)*32 + ((L>>2)&3)*8 + (cf&1)*4 + (L&3)
__global__ __launch_bounds__(256) void gemm_qkv(const ushort* __restrict__ Wb,
                                                const ushort* __restrict__ hnT,
                                                const float* __restrict__ qkvb,
                                                ushort* __restrict__ qT,
                                                ushort* __restrict__ kT,
                                                ushort* __restrict__ vb) {
    int lane = threadIdx.x & 63, wave = threadIdx.x >> 6;
    int l15 = lane & 15, lg = lane >> 4;
    int bi = blockIdx.x;
    int b = bi & 7;
    int slot = bi >> 3;
    int m0 = (slot % 12) * 128;
    int n0 = (slot / 12) * 128;
    int mw = (wave >> 1) * 64, nw = (wave & 1) * 64;
    const ushort* bb = hnT + (size_t)b * 524288;

    __shared__ ushort abuf[2][8192];
    __shared__ ushort bbuf[2][8192];

    f32x4 acc[4][4] = {};
    stage_tile64(abuf[0], Wb + (size_t)m0 * 512, 512, 16, wave, lane);
    stage_tile64(bbuf[0], bb + (size_t)n0 * 512, 512, 16, wave, lane);
    __syncthreads();
    int cur = 0;
#pragma unroll 1
    for (int t = 0; t < 8; ++t) {
        if (t < 7) {
            stage_tile64(abuf[cur ^ 1], Wb + (size_t)m0 * 512 + (t + 1) * 64, 512, 16, wave, lane);
            stage_tile64(bbuf[cur ^ 1], bb + (size_t)n0 * 512 + (t + 1) * 64, 512, 16, wave, lane);
        }
#pragma unroll
        for (int kh = 0; kh < 2; kh++) {
            bf16x8 af[4], bfr[4];
#pragma unroll
            for (int i = 0; i < 4; i++)
                af[i] = lds_read_row(abuf[cur], mw + i * 16 + l15, kh * 64 + lg * 16);
#pragma unroll
            for (int j = 0; j < 4; j++)
                bfr[j] = lds_read_row(bbuf[cur], nw + j * 16 + l15, kh * 64 + lg * 16);
#pragma unroll
            for (int i = 0; i < 4; i++)
#pragma unroll
                for (int j = 0; j < 4; j++)
                    acc[i][j] = MFMA(af[i], bfr[j], acc[i][j]);
        }
        __syncthreads();
        cur ^= 1;
    }

#pragma unroll
    for (int i = 0; i < 4; i++) {
        int ob = m0 + mw + i * 16 + lg * 4;
        float bias[4];
#pragma unroll
        for (int r = 0; r < 4; r++) bias[r] = qkvb[ob + r];
        int part = ob >> 9;
        int oo = ob & 511;
#pragma unroll
        for (int j = 0; j < 4; j++) {
            int n = n0 + nw + j * 16 + l15;
            if (part == 2) {
                int L = n & 63;
                int cf = L >> 4;
                int s = ((cf >> 1) << 5) | (((L >> 2) & 3) << 3) | ((cf & 1) << 2) | (L & 3);
                int np = (n & ~63) | s;
#pragma unroll
                for (int r = 0; r < 4; r++)
                    vb[(size_t)(b * 512 + oo + r) * 1024 + np] = f2bf(acc[i][j][r] + bias[r]);
            } else {
                ushort* dst = part ? kT : qT;
                float sc = part ? 1.0f : CS;      // pre-scale Q by 0.125*log2(e)
                int h = oo >> 6, dd = oo & 63;
                ushort4 p;
                p.x = f2bf((acc[i][j][0] + bias[0]) * sc);
                p.y = f2bf((acc[i][j][1] + bias[1]) * sc);
                p.z = f2bf((acc[i][j][2] + bias[2]) * sc);
                p.w = f2bf((acc[i][j][3] + bias[3]) * sc);
                *(ushort4*)(dst + ((size_t)((b * 8 + h) * 1024 + n)) * 64 + dd) = p;
            }
        }
    }
}

// ---------------------------------------------------------------- attention
// 128 q-rows/block (4 waves x 32 rows); K/V 64-row tiles double-buffered in LDS
// (global_load_lds, XOR-swizzled). Swapped QK^T (mfma(K,Q) -> S^T) makes each
// lane hold P[q=l15][kv=cf*16+lg*4+r]; with V's kv-axis pre-permuted by pi^-1
// (in gemm_qkv), those registers ARE the PV A-fragments: P never touches LDS.
// Q pre-scaled: P = exp2(S). Row sums via ones-MFMA.
__global__ __launch_bounds__(256) void attn_kernel(const ushort* __restrict__ qT,
                                                   const ushort* __restrict__ kT,
                                                   const ushort* __restrict__ vb,
                                                   ushort* __restrict__ aoT) {
    int bi = blockIdx.x;
    int bh = ((bi >> 6) << 3) | (bi & 7);
    int q0 = ((bi >> 3) & 7) * 128;
    int b = bh >> 3, h = bh & 7;
    int lane = threadIdx.x & 63, wave = threadIdx.x >> 6;
    int l15 = lane & 15, lg = lane >> 4;
    const ushort* qp = qT + (size_t)bh * 65536;
    const ushort* kp = kT + (size_t)bh * 65536;
    const ushort* vp = vb + (size_t)bh * 65536;

    __shared__ ushort kbuf[2][4096];   // [kv 64][d 64]
    __shared__ ushort vbuf[2][4096];   // [dd 64][kv-slot 64] (pi-permuted)

    bf16x8 vone;
#pragma unroll
    for (int e = 0; e < 8; e++) vone[e] = (__bf16)1.0f;

    bf16x8 qf[2][2];
#pragma unroll
    for (int i = 0; i < 2; i++)
#pragma unroll
        for (int kh = 0; kh < 2; kh++)
            qf[i][kh] = *(const bf16x8*)(qp + (size_t)(q0 + wave * 32 + i * 16 + l15) * 64 + kh * 32 + lg * 8);

    f32x4 oacc[2][4] = {};
    f32x4 lacc[2] = {};

    stage_tile64(kbuf[0], kp, 64, 8, wave, lane);
    stage_tile64(vbuf[0], vp, 1024, 8, wave, lane);
    __syncthreads();
    int cur = 0;

#pragma unroll 1
    for (int t = 0; t < 16; ++t) {
        if (t < 15) {
            stage_tile64(kbuf[cur ^ 1], kp + (size_t)(t + 1) * 4096, 64, 8, wave, lane);
            stage_tile64(vbuf[cur ^ 1], vp + (t + 1) * 64, 1024, 8, wave, lane);
        }
        const ushort* kb = kbuf[cur];
        const ushort* vc = vbuf[cur];

        // S^T = K Q^T : sacc[i][cf] D[kv=cf*16+lg*4+r][q=i*16+l15]
        f32x4 sacc[2][4] = {};
        __builtin_amdgcn_s_setprio(1);
#pragma unroll
        for (int kh = 0; kh < 2; kh++)
#pragma unroll
            for (int cf = 0; cf < 4; cf++) {
                bf16x8 kf = lds_read_row(kb, cf * 16 + l15, kh * 64 + lg * 16);
                sacc[0][cf] = MFMA(kf, qf[0][kh], sacc[0][cf]);
                sacc[1][cf] = MFMA(kf, qf[1][kh], sacc[1][cf]);
            }
        __builtin_amdgcn_s_setprio(0);

        // V fragments (B-operand; vbuf columns are pi-permuted kv slots)
        bf16x8 vf[2][4];
#pragma unroll
        for (int ks = 0; ks < 2; ks++)
#pragma unroll
            for (int cf = 0; cf < 4; cf++)
                vf[ks][cf] = lds_read_row(vc, cf * 16 + l15, ks * 64 + lg * 16);

        // P = exp2(S^T) packed directly into PV A-fragments (in-register):
        // pa[i][ks][j] = P[q=l15][kv = (ks*2+(j>>2))*16 + lg*4 + (j&3)]
        bf16x8 pa[2][2];
#pragma unroll
        for (int i = 0; i < 2; i++)
#pragma unroll
            for (int ks = 0; ks < 2; ks++) {
                bf16x8 tr;
#pragma unroll
                for (int jhi = 0; jhi < 2; jhi++)
#pragma unroll
                    for (int r = 0; r < 4; r++)
                        tr[jhi * 4 + r] = (__bf16)exp2f(sacc[i][ks * 2 + jhi][r]);
                pa[i][ks] = tr;
            }

        __builtin_amdgcn_s_setprio(1);
#pragma unroll
        for (int i = 0; i < 2; i++)
#pragma unroll
            for (int ks = 0; ks < 2; ks++) {
                lacc[i] = MFMA(pa[i][ks], vone, lacc[i]);   // row sums on matrix pipe
#pragma unroll
                for (int cf = 0; cf < 4; cf++)
                    oacc[i][cf] = MFMA(pa[i][ks], vf[ks][cf], oacc[i][cf]);
            }
        __builtin_amdgcn_s_setprio(0);
        __syncthreads();
        cur ^= 1;
    }

#pragma unroll
    for (int i = 0; i < 2; i++)
#pragma unroll
        for (int r = 0; r < 4; r++) {
            float inv = 1.0f / lacc[i][r];
            int n = q0 + wave * 32 + i * 16 + lg * 4 + r;
            size_t obase = ((size_t)b * 1024 + n) * 512 + h * 64;
#pragma unroll
            for (int cf = 0; cf < 4; cf++)
                aoT[obase + cf * 16 + l15] = f2bf(oacc[i][cf][r] * inv);
        }
}

// ---------------------------------------------------------------- proj GEMM + residual
__global__ __launch_bounds__(256) void gemm_proj(const ushort* __restrict__ Wb,
                                                 const ushort* __restrict__ aoT,
                                                 const float* __restrict__ projb,
                                                 const float* __restrict__ x,
                                                 float* __restrict__ out) {
    int lane = threadIdx.x & 63, wave = threadIdx.x >> 6;
    int l15 = lane & 15, lg = lane >> 4;
    int bi = blockIdx.x;
    int b = bi & 7;
    int slot = bi >> 3;
    int m0 = (slot & 3) * 128;
    int n0 = (slot >> 2) * 64;
    int mw = (wave >> 1) * 64, nw = (wave & 1) * 32;
    const ushort* bb = aoT + (size_t)b * 524288;

    __shared__ ushort abuf[2][8192];
    __shared__ ushort bbuf[2][4096];

    f32x4 acc[4][2] = {};
    stage_tile64(abuf[0], Wb + (size_t)m0 * 512, 512, 16, wave, lane);
    stage_tile64(bbuf[0], bb + (size_t)n0 * 512, 512, 8, wave, lane);
    __syncthreads();
    int cur = 0;
#pragma unroll 1
    for (int t = 0; t < 8; ++t) {
        if (t < 7) {
            stage_tile64(abuf[cur ^ 1], Wb + (size_t)m0 * 512 + (t + 1) * 64, 512, 16, wave, lane);
            stage_tile64(bbuf[cur ^ 1], bb + (size_t)n0 * 512 + (t + 1) * 64, 512, 8, wave, lane);
        }
#pragma unroll
        for (int kh = 0; kh < 2; kh++) {
            bf16x8 af[4], bfr[2];
#pragma unroll
            for (int i = 0; i < 4; i++)
                af[i] = lds_read_row(abuf[cur], mw + i * 16 + l15, kh * 64 + lg * 16);
#pragma unroll
            for (int j = 0; j < 2; j++)
                bfr[j] = lds_read_row(bbuf[cur], nw + j * 16 + l15, kh * 64 + lg * 16);
#pragma unroll
            for (int i = 0; i < 4; i++)
#pragma unroll
                for (int j = 0; j < 2; j++)
                    acc[i][j] = MFMA(af[i], bfr[j], acc[i][j]);
        }
        __syncthreads();
        cur ^= 1;
    }

#pragma unroll
    for (int i = 0; i < 4; i++) {
        int ob = m0 + mw + i * 16 + lg * 4;
        float bias[4];
#pragma unroll
        for (int r = 0; r < 4; r++) bias[r] = projb[ob + r];
#pragma unroll
        for (int j = 0; j < 2; j++) {
            int n = n0 + nw + j * 16 + l15;
#pragma unroll
            for (int r = 0; r < 4; r++) {
                size_t idx = (size_t)(b * 512 + ob + r) * 1024 + n;
                out[idx] = x[idx] + bias[r] + acc[i][j][r];
            }
        }
    }
}

// ---------------------------------------------------------------- launcher
extern "C" void kernel_launch(void* const* d_in, const int* in_sizes, int n_in,
                              void* d_out, int out_size, void* d_ws, size_t ws_size,
                              hipStream_t stream) {
    const float* x     = (const float*)d_in[0];
    const float* gnw   = (const float*)d_in[1];
    const float* gnb   = (const float*)d_in[2];
    const float* qkvw  = (const float*)d_in[3];
    const float* qkvb  = (const float*)d_in[4];
    const float* projw = (const float*)d_in[5];
    const float* projb = (const float*)d_in[6];
    float* out = (float*)d_out;

    char* ws = (char*)d_ws;
    ushort* hnT    = (ushort*)(ws);                          // 8 MB (reused as aoT)
    ushort* qT     = (ushort*)(ws + (size_t)(8u << 20));     // 8 MB
    ushort* kT     = (ushort*)(ws + (size_t)(16u << 20));    // 8 MB
    ushort* vbuf   = (ushort*)(ws + (size_t)(24u << 20));    // 8 MB
    ushort* qkvwb  = (ushort*)(ws + (size_t)(32u << 20));    // 1.5 MB
    ushort* projwb = (ushort*)(ws + (size_t)(32u << 20) + 1572864);  // 0.5 MB

    gn_cvt_kernel<<<dim3(1280), dim3(256), 0, stream>>>(x, gnw, gnb, hnT,
                                                        qkvw, projw, qkvwb, projwb);
    gemm_qkv<<<dim3(768), dim3(256), 0, stream>>>(qkvwb, hnT, qkvb, qT, kT, vbuf);
    attn_kernel<<<dim3(512), dim3(256), 0, stream>>>(qT, kT, vbuf, hnT /* aoT */);
    gemm_proj<<<dim3(512), dim3(256), 0, stream>>>(projwb, hnT, projb, x, out);
}

// Round 10
// 86.705 us; speedup vs baseline: 1.3695x; 1.0165x over previous
//
#include <hip/hip_runtime.h>

typedef __bf16 bf16x8 __attribute__((ext_vector_type(8)));
typedef float f32x4 __attribute__((ext_vector_type(4)));

#define MFMA(a, b, c) __builtin_amdgcn_mfma_f32_16x16x32_bf16(a, b, c, 0, 0, 0)

#define CS 0.18033688011112042f   /* 0.125 * log2(e) */

__device__ __forceinline__ ushort f2bf(float f) {
    __bf16 h = (__bf16)f;
    return *(ushort*)&h;
}

// ---- stage an (8*nchunks)-row x 64-col bf16 tile into LDS, XOR-swizzled ----
__device__ __forceinline__ void stage_tile64(ushort* lds, const ushort* gbase,
                                             int row_stride, int nchunks,
                                             int wave, int lane) {
    int r8 = lane >> 3;
    int cswz = ((lane & 7) ^ r8) << 4;
#pragma unroll
    for (int c = wave; c < nchunks; c += 4) {
        const char* g = (const char*)(gbase + (size_t)(c * 8 + r8) * row_stride) + cswz;
        __builtin_amdgcn_global_load_lds(
            (const __attribute__((address_space(1))) unsigned int*)g,
            (__attribute__((address_space(3))) unsigned int*)((char*)lds + c * 1024),
            16, 0, 0);
    }
}

__device__ __forceinline__ bf16x8 lds_read_row(const ushort* lds, int row, int cb) {
    return *(const bf16x8*)((const char*)lds + row * 128 + (cb ^ ((row & 7) << 4)));
}

// ---------------------------------------------------------------- groupnorm (+fused weight cvt)
__global__ __launch_bounds__(256) void gn_cvt_kernel(const float* __restrict__ x,
                                                     const float* __restrict__ gnw,
                                                     const float* __restrict__ gnb,
                                                     ushort* __restrict__ hnT,
                                                     const float* __restrict__ w1,
                                                     const float* __restrict__ w2,
                                                     ushort* __restrict__ o1,
                                                     ushort* __restrict__ o2) {
    if (blockIdx.x >= 256) {
        int t = (blockIdx.x - 256) * 256 + threadIdx.x;
        const int n1q = (1536 * 512) / 4;
        float4 v;
        ushort* dst;
        int idx;
        if (t < n1q) {
            v = ((const float4*)w1)[t]; dst = o1; idx = t;
        } else {
            idx = t - n1q;
            v = ((const float4*)w2)[idx]; dst = o2;
        }
        ushort4 p;
        p.x = f2bf(v.x); p.y = f2bf(v.y); p.z = f2bf(v.z); p.w = f2bf(v.w);
        ((ushort4*)dst)[idx] = p;
        return;
    }

    int b = blockIdx.x >> 5, g = blockIdx.x & 31;
    const float* xp = x + (size_t)(b * 512 + g * 16) * 1024;
    int t = threadIdx.x;

    float s = 0.f, ss = 0.f;
    const float4* xp4 = (const float4*)xp;
    for (int i = t; i < 4096; i += 256) {
        float4 v = xp4[i];
        s += (v.x + v.y) + (v.z + v.w);
        ss += (v.x * v.x + v.y * v.y) + (v.z * v.z + v.w * v.w);
    }
#pragma unroll
    for (int off = 32; off >= 1; off >>= 1) {
        s += __shfl_xor(s, off);
        ss += __shfl_xor(ss, off);
    }
    __shared__ float red[8];
    __shared__ float sw[16], sb[16];
    int wave = t >> 6;
    if ((t & 63) == 0) { red[wave] = s; red[wave + 4] = ss; }
    if (t < 16) { sw[t] = gnw[g * 16 + t]; sb[t] = gnb[g * 16 + t]; }
    __syncthreads();
    float S = red[0] + red[1] + red[2] + red[3];
    float SS = red[4] + red[5] + red[6] + red[7];
    float mean = S * (1.0f / 16384.0f);
    float var = SS * (1.0f / 16384.0f) - mean * mean;
    float rstd = rsqrtf(var + 1e-5f);

    __shared__ ushort tile[16][258];
    int cc0 = (t & 3) * 4;
    int nb = t >> 2;
    for (int chunk = 0; chunk < 4; ++chunk) {
        __syncthreads();
#pragma unroll
        for (int cc = 0; cc < 16; ++cc) {
            float v = xp[cc * 1024 + chunk * 256 + t];
            tile[cc][t] = f2bf((v - mean) * rstd * sw[cc] + sb[cc]);
        }
        __syncthreads();
        size_t rowbase = (size_t)b * 1024 + chunk * 256;
#pragma unroll
        for (int k = 0; k < 4; ++k) {
            int nl = nb + 64 * k;
            ushort4 p;
            p.x = tile[cc0 + 0][nl];
            p.y = tile[cc0 + 1][nl];
            p.z = tile[cc0 + 2][nl];
            p.w = tile[cc0 + 3][nl];
            *(ushort4*)(hnT + (rowbase + nl) * 512 + g * 16 + cc0) = p;
        }
    }
}

// ---------------------------------------------------------------- QKV GEMM
// V written with kv-axis permuted within each 64-token block by pi^-1 so that
// attention's in-register P fragments contract correctly:
//   L = n&63; cf=L>>4; s = (cf>>1)*32 + ((L>>2)&3)*8 + (cf&1)*4 + (L&3)
__global__ __launch_bounds__(256) void gemm_qkv(const ushort* __restrict__ Wb,
                                                const ushort* __restrict__ hnT,
                                                const float* __restrict__ qkvb,
                                                ushort* __restrict__ qT,
                                                ushort* __restrict__ kT,
                                                ushort* __restrict__ vb) {
    int lane = threadIdx.x & 63, wave = threadIdx.x >> 6;
    int l15 = lane & 15, lg = lane >> 4;
    int bi = blockIdx.x;
    int b = bi & 7;
    int slot = bi >> 3;
    int m0 = (slot % 12) * 128;
    int n0 = (slot / 12) * 128;
    int mw = (wave >> 1) * 64, nw = (wave & 1) * 64;
    const ushort* bb = hnT + (size_t)b * 524288;

    __shared__ ushort abuf[2][8192];
    __shared__ ushort bbuf[2][8192];

    f32x4 acc[4][4] = {};
    stage_tile64(abuf[0], Wb + (size_t)m0 * 512, 512, 16, wave, lane);
    stage_tile64(bbuf[0], bb + (size_t)n0 * 512, 512, 16, wave, lane);
    __syncthreads();
    int cur = 0;
#pragma unroll 1
    for (int t = 0; t < 8; ++t) {
        if (t < 7) {
            stage_tile64(abuf[cur ^ 1], Wb + (size_t)m0 * 512 + (t + 1) * 64, 512, 16, wave, lane);
            stage_tile64(bbuf[cur ^ 1], bb + (size_t)n0 * 512 + (t + 1) * 64, 512, 16, wave, lane);
        }
#pragma unroll
        for (int kh = 0; kh < 2; kh++) {
            bf16x8 af[4], bfr[4];
#pragma unroll
            for (int i = 0; i < 4; i++)
                af[i] = lds_read_row(abuf[cur], mw + i * 16 + l15, kh * 64 + lg * 16);
#pragma unroll
            for (int j = 0; j < 4; j++)
                bfr[j] = lds_read_row(bbuf[cur], nw + j * 16 + l15, kh * 64 + lg * 16);
#pragma unroll
            for (int i = 0; i < 4; i++)
#pragma unroll
                for (int j = 0; j < 4; j++)
                    acc[i][j] = MFMA(af[i], bfr[j], acc[i][j]);
        }
        __syncthreads();
        cur ^= 1;
    }

#pragma unroll
    for (int i = 0; i < 4; i++) {
        int ob = m0 + mw + i * 16 + lg * 4;
        float bias[4];
#pragma unroll
        for (int r = 0; r < 4; r++) bias[r] = qkvb[ob + r];
        int part = ob >> 9;
        int oo = ob & 511;
#pragma unroll
        for (int j = 0; j < 4; j++) {
            int n = n0 + nw + j * 16 + l15;
            if (part == 2) {
                int L = n & 63;
                int cf = L >> 4;
                int s = ((cf >> 1) << 5) | (((L >> 2) & 3) << 3) | ((cf & 1) << 2) | (L & 3);
                int np = (n & ~63) | s;
#pragma unroll
                for (int r = 0; r < 4; r++)
                    vb[(size_t)(b * 512 + oo + r) * 1024 + np] = f2bf(acc[i][j][r] + bias[r]);
            } else {
                ushort* dst = part ? kT : qT;
                float sc = part ? 1.0f : CS;      // pre-scale Q by 0.125*log2(e)
                int h = oo >> 6, dd = oo & 63;
                ushort4 p;
                p.x = f2bf((acc[i][j][0] + bias[0]) * sc);
                p.y = f2bf((acc[i][j][1] + bias[1]) * sc);
                p.z = f2bf((acc[i][j][2] + bias[2]) * sc);
                p.w = f2bf((acc[i][j][3] + bias[3]) * sc);
                *(ushort4*)(dst + ((size_t)((b * 8 + h) * 1024 + n)) * 64 + dd) = p;
            }
        }
    }
}

// ---------------------------------------------------------------- attention
// 128 q-rows/block (4 waves x 32 rows). K/V TRIPLE-buffered in LDS with
// counted-vmcnt pipeline (T3/T4): stage tile t+2 each iteration, end with
// s_waitcnt vmcnt(4) (t+2's 4 loads stay in flight; t+1's are complete) +
// raw s_barrier -- never a full drain in the main loop. Each wave issues
// exactly 4 global_load_lds per tile (2 K chunks + 2 V chunks), so the
// symmetric count makes the barrier sufficient for cross-wave LDS visibility.
// Swapped QK^T (mfma(K,Q) -> S^T) keeps P entirely in registers (V kv-axis
// pre-permuted by pi^-1 in gemm_qkv). Q pre-scaled: P = exp2(S). Row sums
// via ones-MFMA.
__global__ __launch_bounds__(256) void attn_kernel(const ushort* __restrict__ qT,
                                                   const ushort* __restrict__ kT,
                                                   const ushort* __restrict__ vb,
                                                   ushort* __restrict__ aoT) {
    int bi = blockIdx.x;
    int bh = ((bi >> 6) << 3) | (bi & 7);
    int q0 = ((bi >> 3) & 7) * 128;
    int b = bh >> 3, h = bh & 7;
    int lane = threadIdx.x & 63, wave = threadIdx.x >> 6;
    int l15 = lane & 15, lg = lane >> 4;
    const ushort* qp = qT + (size_t)bh * 65536;
    const ushort* kp = kT + (size_t)bh * 65536;
    const ushort* vp = vb + (size_t)bh * 65536;

    __shared__ ushort kbuf[3][4096];   // [kv 64][d 64]
    __shared__ ushort vbuf[3][4096];   // [dd 64][kv-slot 64] (pi-permuted)

    bf16x8 vone;
#pragma unroll
    for (int e = 0; e < 8; e++) vone[e] = (__bf16)1.0f;

    bf16x8 qf[2][2];
#pragma unroll
    for (int i = 0; i < 2; i++)
#pragma unroll
        for (int kh = 0; kh < 2; kh++)
            qf[i][kh] = *(const bf16x8*)(qp + (size_t)(q0 + wave * 32 + i * 16 + l15) * 64 + kh * 32 + lg * 8);

    f32x4 oacc[2][4] = {};
    f32x4 lacc[2] = {};

    // prologue: stage tiles 0 and 1 (8 loads/wave outstanding)
    stage_tile64(kbuf[0], kp, 64, 8, wave, lane);
    stage_tile64(vbuf[0], vp, 1024, 8, wave, lane);
    stage_tile64(kbuf[1], kp + 4096, 64, 8, wave, lane);
    stage_tile64(vbuf[1], vp + 64, 1024, 8, wave, lane);
    asm volatile("s_waitcnt vmcnt(4)" ::: "memory");   // tile 0 resident
    __builtin_amdgcn_s_barrier();

    int cur = 0;
#pragma unroll 1
    for (int t = 0; t < 16; ++t) {
        if (t < 14) {
            int nxt = cur + 2; if (nxt >= 3) nxt -= 3;
            stage_tile64(kbuf[nxt], kp + (size_t)(t + 2) * 4096, 64, 8, wave, lane);
            stage_tile64(vbuf[nxt], vp + (t + 2) * 64, 1024, 8, wave, lane);
        }
        const ushort* kb = kbuf[cur];
        const ushort* vc = vbuf[cur];

        // S^T = K Q^T : sacc[i][cf] D[kv=cf*16+lg*4+r][q=i*16+l15]
        f32x4 sacc[2][4] = {};
        __builtin_amdgcn_s_setprio(1);
#pragma unroll
        for (int kh = 0; kh < 2; kh++)
#pragma unroll
            for (int cf = 0; cf < 4; cf++) {
                bf16x8 kf = lds_read_row(kb, cf * 16 + l15, kh * 64 + lg * 16);
                sacc[0][cf] = MFMA(kf, qf[0][kh], sacc[0][cf]);
                sacc[1][cf] = MFMA(kf, qf[1][kh], sacc[1][cf]);
            }
        __builtin_amdgcn_s_setprio(0);

        // V fragments (B-operand; vbuf columns are pi-permuted kv slots)
        bf16x8 vf[2][4];
#pragma unroll
        for (int ks = 0; ks < 2; ks++)
#pragma unroll
            for (int cf = 0; cf < 4; cf++)
                vf[ks][cf] = lds_read_row(vc, cf * 16 + l15, ks * 64 + lg * 16);

        // P = exp2(S^T) packed directly into PV A-fragments (in-register)
        bf16x8 pa[2][2];
#pragma unroll
        for (int i = 0; i < 2; i++)
#pragma unroll
            for (int ks = 0; ks < 2; ks++) {
                bf16x8 tr;
#pragma unroll
                for (int jhi = 0; jhi < 2; jhi++)
#pragma unroll
                    for (int r = 0; r < 4; r++)
                        tr[jhi * 4 + r] = (__bf16)exp2f(sacc[i][ks * 2 + jhi][r]);
                pa[i][ks] = tr;
            }

        __builtin_amdgcn_s_setprio(1);
#pragma unroll
        for (int i = 0; i < 2; i++)
#pragma unroll
            for (int ks = 0; ks < 2; ks++) {
                lacc[i] = MFMA(pa[i][ks], vone, lacc[i]);   // row sums on matrix pipe
#pragma unroll
                for (int cf = 0; cf < 4; cf++)
                    oacc[i][cf] = MFMA(pa[i][ks], vf[ks][cf], oacc[i][cf]);
            }
        __builtin_amdgcn_s_setprio(0);

        if (t < 15) {
            if (t < 14) asm volatile("s_waitcnt vmcnt(4)" ::: "memory");  // t+1 resident
            else        asm volatile("s_waitcnt vmcnt(0)" ::: "memory");  // tail
            __builtin_amdgcn_s_barrier();
        }
        cur = cur + 1; if (cur == 3) cur = 0;
    }

#pragma unroll
    for (int i = 0; i < 2; i++)
#pragma unroll
        for (int r = 0; r < 4; r++) {
            float inv = 1.0f / lacc[i][r];
            int n = q0 + wave * 32 + i * 16 + lg * 4 + r;
            size_t obase = ((size_t)b * 1024 + n) * 512 + h * 64;
#pragma unroll
            for (int cf = 0; cf < 4; cf++)
                aoT[obase + cf * 16 + l15] = f2bf(oacc[i][cf][r] * inv);
        }
}

// ---------------------------------------------------------------- proj GEMM + residual
__global__ __launch_bounds__(256) void gemm_proj(const ushort* __restrict__ Wb,
                                                 const ushort* __restrict__ aoT,
                                                 const float* __restrict__ projb,
                                                 const float* __restrict__ x,
                                                 float* __restrict__ out) {
    int lane = threadIdx.x & 63, wave = threadIdx.x >> 6;
    int l15 = lane & 15, lg = lane >> 4;
    int bi = blockIdx.x;
    int b = bi & 7;
    int slot = bi >> 3;
    int m0 = (slot & 3) * 128;
    int n0 = (slot >> 2) * 64;
    int mw = (wave >> 1) * 64, nw = (wave & 1) * 32;
    const ushort* bb = aoT + (size_t)b * 524288;

    __shared__ ushort abuf[2][8192];
    __shared__ ushort bbuf[2][4096];

    f32x4 acc[4][2] = {};
    stage_tile64(abuf[0], Wb + (size_t)m0 * 512, 512, 16, wave, lane);
    stage_tile64(bbuf[0], bb + (size_t)n0 * 512, 512, 8, wave, lane);
    __syncthreads();
    int cur = 0;
#pragma unroll 1
    for (int t = 0; t < 8; ++t) {
        if (t < 7) {
            stage_tile64(abuf[cur ^ 1], Wb + (size_t)m0 * 512 + (t + 1) * 64, 512, 16, wave, lane);
            stage_tile64(bbuf[cur ^ 1], bb + (size_t)n0 * 512 + (t + 1) * 64, 512, 8, wave, lane);
        }
#pragma unroll
        for (int kh = 0; kh < 2; kh++) {
            bf16x8 af[4], bfr[2];
#pragma unroll
            for (int i = 0; i < 4; i++)
                af[i] = lds_read_row(abuf[cur], mw + i * 16 + l15, kh * 64 + lg * 16);
#pragma unroll
            for (int j = 0; j < 2; j++)
                bfr[j] = lds_read_row(bbuf[cur], nw + j * 16 + l15, kh * 64 + lg * 16);
#pragma unroll
            for (int i = 0; i < 4; i++)
#pragma unroll
                for (int j = 0; j < 2; j++)
                    acc[i][j] = MFMA(af[i], bfr[j], acc[i][j]);
        }
        __syncthreads();
        cur ^= 1;
    }

#pragma unroll
    for (int i = 0; i < 4; i++) {
        int ob = m0 + mw + i * 16 + lg * 4;
        float bias[4];
#pragma unroll
        for (int r = 0; r < 4; r++) bias[r] = projb[ob + r];
#pragma unroll
        for (int j = 0; j < 2; j++) {
            int n = n0 + nw + j * 16 + l15;
#pragma unroll
            for (int r = 0; r < 4; r++) {
                size_t idx = (size_t)(b * 512 + ob + r) * 1024 + n;
                out[idx] = x[idx] + bias[r] + acc[i][j][r];
            }
        }
    }
}

// ---------------------------------------------------------------- launcher
extern "C" void kernel_launch(void* const* d_in, const int* in_sizes, int n_in,
                              void* d_out, int out_size, void* d_ws, size_t ws_size,
                              hipStream_t stream) {
    const float* x     = (const float*)d_in[0];
    const float* gnw   = (const float*)d_in[1];
    const float* gnb   = (const float*)d_in[2];
    const float* qkvw  = (const float*)d_in[3];
    const float* qkvb  = (const float*)d_in[4];
    const float* projw = (const float*)d_in[5];
    const float* projb = (const float*)d_in[6];
    float* out = (float*)d_out;

    char* ws = (char*)d_ws;
    ushort* hnT    = (ushort*)(ws);                          // 8 MB (reused as aoT)
    ushort* qT     = (ushort*)(ws + (size_t)(8u << 20));     // 8 MB
    ushort* kT     = (ushort*)(ws + (size_t)(16u << 20));    // 8 MB
    ushort* vbuf   = (ushort*)(ws + (size_t)(24u << 20));    // 8 MB
    ushort* qkvwb  = (ushort*)(ws + (size_t)(32u << 20));    // 1.5 MB
    ushort* projwb = (ushort*)(ws + (size_t)(32u << 20) + 1572864);  // 0.5 MB

    gn_cvt_kernel<<<dim3(1280), dim3(256), 0, stream>>>(x, gnw, gnb, hnT,
                                                        qkvw, projw, qkvwb, projwb);
    gemm_qkv<<<dim3(768), dim3(256), 0, stream>>>(qkvwb, hnT, qkvb, qT, kT, vbuf);
    attn_kernel<<<dim3(512), dim3(256), 0, stream>>>(qT, kT, vbuf, hnT /* aoT */);
    gemm_proj<<<dim3(512), dim3(256), 0, stream>>>(projwb, hnT, projb, x, out);
}

// Round 11
// 86.379 us; speedup vs baseline: 1.3747x; 1.0038x over previous
//
#include <hip/hip_runtime.h>

typedef __bf16 bf16x8 __attribute__((ext_vector_type(8)));
typedef float f32x4 __attribute__((ext_vector_type(4)));

#define MFMA(a, b, c) __builtin_amdgcn_mfma_f32_16x16x32_bf16(a, b, c, 0, 0, 0)

#define CS 0.18033688011112042f   /* 0.125 * log2(e) */

__device__ __forceinline__ ushort f2bf(float f) {
    __bf16 h = (__bf16)f;
    return *(ushort*)&h;
}

// ---- stage (8*nchunks)-row x 64-col bf16 tile into LDS, XOR-swizzled (128B rows)
__device__ __forceinline__ void stage_tile64(ushort* lds, const ushort* gbase,
                                             int row_stride, int nchunks,
                                             int wave, int lane) {
    int r8 = lane >> 3;
    int cswz = ((lane & 7) ^ r8) << 4;
#pragma unroll
    for (int c = wave; c < nchunks; c += 4) {
        const char* g = (const char*)(gbase + (size_t)(c * 8 + r8) * row_stride) + cswz;
        __builtin_amdgcn_global_load_lds(
            (const __attribute__((address_space(1))) unsigned int*)g,
            (__attribute__((address_space(3))) unsigned int*)((char*)lds + c * 1024),
            16, 0, 0);
    }
}

__device__ __forceinline__ bf16x8 lds_read_row(const ushort* lds, int row, int cb) {
    return *(const bf16x8*)((const char*)lds + row * 128 + (cb ^ ((row & 7) << 4)));
}

// ---- stage (16*nchunks)-row x 32-col bf16 tile into LDS, XOR-swizzled (64B rows)
// swizzle: physical 16B-slot = logical slot ^ ((row>>1)&3)  -> ds_read_b128 of a
// 16-row column slice lands on 8 distinct banks, 2-way alias (free, m136).
__device__ __forceinline__ void stage_tile32(ushort* lds, const ushort* gbase,
                                             int row_stride, int nchunks,
                                             int wave, int lane) {
    int r16 = lane >> 2;                                   // row within 16-row chunk
    int csw = (((lane & 3) ^ ((lane >> 3) & 3)) << 3);     // pre-swizzled src col (ushorts)
#pragma unroll
    for (int c = wave; c < nchunks; c += 4) {
        const ushort* g = gbase + (size_t)(c * 16 + r16) * row_stride + csw;
        __builtin_amdgcn_global_load_lds(
            (const __attribute__((address_space(1))) unsigned int*)g,
            (__attribute__((address_space(3))) unsigned int*)((char*)lds + c * 1024),
            16, 0, 0);
    }
}

__device__ __forceinline__ bf16x8 lds_read_row32(const ushort* lds, int row, int cb) {
    return *(const bf16x8*)((const char*)lds + row * 64 + (cb ^ (((row >> 1) & 3) << 4)));
}

// ---------------------------------------------------------------- groupnorm (+fused weight cvt)
__global__ __launch_bounds__(256) void gn_cvt_kernel(const float* __restrict__ x,
                                                     const float* __restrict__ gnw,
                                                     const float* __restrict__ gnb,
                                                     ushort* __restrict__ hnT,
                                                     const float* __restrict__ w1,
                                                     const float* __restrict__ w2,
                                                     ushort* __restrict__ o1,
                                                     ushort* __restrict__ o2) {
    if (blockIdx.x >= 256) {
        int t = (blockIdx.x - 256) * 256 + threadIdx.x;
        const int n1q = (1536 * 512) / 4;
        float4 v;
        ushort* dst;
        int idx;
        if (t < n1q) {
            v = ((const float4*)w1)[t]; dst = o1; idx = t;
        } else {
            idx = t - n1q;
            v = ((const float4*)w2)[idx]; dst = o2;
        }
        ushort4 p;
        p.x = f2bf(v.x); p.y = f2bf(v.y); p.z = f2bf(v.z); p.w = f2bf(v.w);
        ((ushort4*)dst)[idx] = p;
        return;
    }

    int b = blockIdx.x >> 5, g = blockIdx.x & 31;
    const float* xp = x + (size_t)(b * 512 + g * 16) * 1024;
    int t = threadIdx.x;

    float s = 0.f, ss = 0.f;
    const float4* xp4 = (const float4*)xp;
    for (int i = t; i < 4096; i += 256) {
        float4 v = xp4[i];
        s += (v.x + v.y) + (v.z + v.w);
        ss += (v.x * v.x + v.y * v.y) + (v.z * v.z + v.w * v.w);
    }
#pragma unroll
    for (int off = 32; off >= 1; off >>= 1) {
        s += __shfl_xor(s, off);
        ss += __shfl_xor(ss, off);
    }
    __shared__ float red[8];
    __shared__ float sw[16], sb[16];
    int wave = t >> 6;
    if ((t & 63) == 0) { red[wave] = s; red[wave + 4] = ss; }
    if (t < 16) { sw[t] = gnw[g * 16 + t]; sb[t] = gnb[g * 16 + t]; }
    __syncthreads();
    float S = red[0] + red[1] + red[2] + red[3];
    float SS = red[4] + red[5] + red[6] + red[7];
    float mean = S * (1.0f / 16384.0f);
    float var = SS * (1.0f / 16384.0f) - mean * mean;
    float rstd = rsqrtf(var + 1e-5f);

    __shared__ ushort tile[16][258];
    int cc0 = (t & 3) * 4;
    int nb = t >> 2;
    for (int chunk = 0; chunk < 4; ++chunk) {
        __syncthreads();
#pragma unroll
        for (int cc = 0; cc < 16; ++cc) {
            float v = xp[cc * 1024 + chunk * 256 + t];
            tile[cc][t] = f2bf((v - mean) * rstd * sw[cc] + sb[cc]);
        }
        __syncthreads();
        size_t rowbase = (size_t)b * 1024 + chunk * 256;
#pragma unroll
        for (int k = 0; k < 4; ++k) {
            int nl = nb + 64 * k;
            ushort4 p;
            p.x = tile[cc0 + 0][nl];
            p.y = tile[cc0 + 1][nl];
            p.z = tile[cc0 + 2][nl];
            p.w = tile[cc0 + 3][nl];
            *(ushort4*)(hnT + (rowbase + nl) * 512 + g * 16 + cc0) = p;
        }
    }
}

// ---------------------------------------------------------------- QKV GEMM
// BK=32, quad-buffered LDS ring, counted-vmcnt pipeline (stage t+3, wait
// vmcnt(8) = 2 tiles in flight, raw barrier -- no drain in steady state).
// V written kv-permuted (pi^-1) for attention's in-register P; Q pre-scaled.
__global__ __launch_bounds__(256) void gemm_qkv(const ushort* __restrict__ Wb,
                                                const ushort* __restrict__ hnT,
                                                const float* __restrict__ qkvb,
                                                ushort* __restrict__ qT,
                                                ushort* __restrict__ kT,
                                                ushort* __restrict__ vb) {
    int lane = threadIdx.x & 63, wave = threadIdx.x >> 6;
    int l15 = lane & 15, lg = lane >> 4;
    int bi = blockIdx.x;
    int b = bi & 7;
    int slot = bi >> 3;
    int m0 = (slot % 12) * 128;
    int n0 = (slot / 12) * 128;
    int mw = (wave >> 1) * 64, nw = (wave & 1) * 64;
    const ushort* Ag = Wb + (size_t)m0 * 512;
    const ushort* Bg = hnT + (size_t)b * 524288 + (size_t)n0 * 512;

    __shared__ ushort abuf[4][4096];   // 128 x 32 each
    __shared__ ushort bbuf[4][4096];

    f32x4 acc[4][4] = {};
    // prologue: stage tiles 0,1,2  (4 loads/wave each)
#pragma unroll
    for (int p = 0; p < 3; ++p) {
        stage_tile32(abuf[p], Ag + p * 32, 512, 8, wave, lane);
        stage_tile32(bbuf[p], Bg + p * 32, 512, 8, wave, lane);
    }
    asm volatile("s_waitcnt vmcnt(8)" ::: "memory");   // tile 0 resident
    __builtin_amdgcn_s_barrier();

#pragma unroll 1
    for (int t = 0; t < 16; ++t) {
        if (t < 13) {
            int nxt = (t + 3) & 3;
            stage_tile32(abuf[nxt], Ag + (t + 3) * 32, 512, 8, wave, lane);
            stage_tile32(bbuf[nxt], Bg + (t + 3) * 32, 512, 8, wave, lane);
        }
        const ushort* A = abuf[t & 3];
        const ushort* B = bbuf[t & 3];
        bf16x8 af[4], bfr[4];
#pragma unroll
        for (int i = 0; i < 4; i++)
            af[i] = lds_read_row32(A, mw + i * 16 + l15, lg * 16);
#pragma unroll
        for (int j = 0; j < 4; j++)
            bfr[j] = lds_read_row32(B, nw + j * 16 + l15, lg * 16);
        __builtin_amdgcn_s_setprio(1);
#pragma unroll
        for (int i = 0; i < 4; i++)
#pragma unroll
            for (int j = 0; j < 4; j++)
                acc[i][j] = MFMA(af[i], bfr[j], acc[i][j]);
        __builtin_amdgcn_s_setprio(0);
        if (t < 15) {
            if (t < 13)      asm volatile("s_waitcnt vmcnt(8)" ::: "memory");
            else if (t == 13) asm volatile("s_waitcnt vmcnt(4)" ::: "memory");
            else              asm volatile("s_waitcnt vmcnt(0)" ::: "memory");
            __builtin_amdgcn_s_barrier();
        }
    }

#pragma unroll
    for (int i = 0; i < 4; i++) {
        int ob = m0 + mw + i * 16 + lg * 4;
        float bias[4];
#pragma unroll
        for (int r = 0; r < 4; r++) bias[r] = qkvb[ob + r];
        int part = ob >> 9;
        int oo = ob & 511;
#pragma unroll
        for (int j = 0; j < 4; j++) {
            int n = n0 + nw + j * 16 + l15;
            if (part == 2) {
                int L = n & 63;
                int cf = L >> 4;
                int s = ((cf >> 1) << 5) | (((L >> 2) & 3) << 3) | ((cf & 1) << 2) | (L & 3);
                int np = (n & ~63) | s;
#pragma unroll
                for (int r = 0; r < 4; r++)
                    vb[(size_t)(b * 512 + oo + r) * 1024 + np] = f2bf(acc[i][j][r] + bias[r]);
            } else {
                ushort* dst = part ? kT : qT;
                float sc = part ? 1.0f : CS;      // pre-scale Q by 0.125*log2(e)
                int h = oo >> 6, dd = oo & 63;
                ushort4 p;
                p.x = f2bf((acc[i][j][0] + bias[0]) * sc);
                p.y = f2bf((acc[i][j][1] + bias[1]) * sc);
                p.z = f2bf((acc[i][j][2] + bias[2]) * sc);
                p.w = f2bf((acc[i][j][3] + bias[3]) * sc);
                *(ushort4*)(dst + ((size_t)((b * 8 + h) * 1024 + n)) * 64 + dd) = p;
            }
        }
    }
}

// ---------------------------------------------------------------- attention
// 128 q-rows/block (4 waves x 32 rows). K/V triple-buffered, counted-vmcnt
// pipeline. Swapped QK^T keeps P in registers (V kv-permuted by pi^-1 in
// gemm_qkv). Q pre-scaled: P = exp2(S). Row sums via ones-MFMA.
__global__ __launch_bounds__(256) void attn_kernel(const ushort* __restrict__ qT,
                                                   const ushort* __restrict__ kT,
                                                   const ushort* __restrict__ vb,
                                                   ushort* __restrict__ aoT) {
    int bi = blockIdx.x;
    int bh = ((bi >> 6) << 3) | (bi & 7);
    int q0 = ((bi >> 3) & 7) * 128;
    int b = bh >> 3, h = bh & 7;
    int lane = threadIdx.x & 63, wave = threadIdx.x >> 6;
    int l15 = lane & 15, lg = lane >> 4;
    const ushort* qp = qT + (size_t)bh * 65536;
    const ushort* kp = kT + (size_t)bh * 65536;
    const ushort* vp = vb + (size_t)bh * 65536;

    __shared__ ushort kbuf[3][4096];   // [kv 64][d 64]
    __shared__ ushort vbuf[3][4096];   // [dd 64][kv-slot 64] (pi-permuted)

    bf16x8 vone;
#pragma unroll
    for (int e = 0; e < 8; e++) vone[e] = (__bf16)1.0f;

    bf16x8 qf[2][2];
#pragma unroll
    for (int i = 0; i < 2; i++)
#pragma unroll
        for (int kh = 0; kh < 2; kh++)
            qf[i][kh] = *(const bf16x8*)(qp + (size_t)(q0 + wave * 32 + i * 16 + l15) * 64 + kh * 32 + lg * 8);

    f32x4 oacc[2][4] = {};
    f32x4 lacc[2] = {};

    stage_tile64(kbuf[0], kp, 64, 8, wave, lane);
    stage_tile64(vbuf[0], vp, 1024, 8, wave, lane);
    stage_tile64(kbuf[1], kp + 4096, 64, 8, wave, lane);
    stage_tile64(vbuf[1], vp + 64, 1024, 8, wave, lane);
    asm volatile("s_waitcnt vmcnt(4)" ::: "memory");   // tile 0 resident
    __builtin_amdgcn_s_barrier();

    int cur = 0;
#pragma unroll 1
    for (int t = 0; t < 16; ++t) {
        if (t < 14) {
            int nxt = cur + 2; if (nxt >= 3) nxt -= 3;
            stage_tile64(kbuf[nxt], kp + (size_t)(t + 2) * 4096, 64, 8, wave, lane);
            stage_tile64(vbuf[nxt], vp + (t + 2) * 64, 1024, 8, wave, lane);
        }
        const ushort* kb = kbuf[cur];
        const ushort* vc = vbuf[cur];

        f32x4 sacc[2][4] = {};
        __builtin_amdgcn_s_setprio(1);
#pragma unroll
        for (int kh = 0; kh < 2; kh++)
#pragma unroll
            for (int cf = 0; cf < 4; cf++) {
                bf16x8 kf = lds_read_row(kb, cf * 16 + l15, kh * 64 + lg * 16);
                sacc[0][cf] = MFMA(kf, qf[0][kh], sacc[0][cf]);
                sacc[1][cf] = MFMA(kf, qf[1][kh], sacc[1][cf]);
            }
        __builtin_amdgcn_s_setprio(0);

        bf16x8 vf[2][4];
#pragma unroll
        for (int ks = 0; ks < 2; ks++)
#pragma unroll
            for (int cf = 0; cf < 4; cf++)
                vf[ks][cf] = lds_read_row(vc, cf * 16 + l15, ks * 64 + lg * 16);

        bf16x8 pa[2][2];
#pragma unroll
        for (int i = 0; i < 2; i++)
#pragma unroll
            for (int ks = 0; ks < 2; ks++) {
                bf16x8 tr;
#pragma unroll
                for (int jhi = 0; jhi < 2; jhi++)
#pragma unroll
                    for (int r = 0; r < 4; r++)
                        tr[jhi * 4 + r] = (__bf16)exp2f(sacc[i][ks * 2 + jhi][r]);
                pa[i][ks] = tr;
            }

        __builtin_amdgcn_s_setprio(1);
#pragma unroll
        for (int i = 0; i < 2; i++)
#pragma unroll
            for (int ks = 0; ks < 2; ks++) {
                lacc[i] = MFMA(pa[i][ks], vone, lacc[i]);   // row sums on matrix pipe
#pragma unroll
                for (int cf = 0; cf < 4; cf++)
                    oacc[i][cf] = MFMA(pa[i][ks], vf[ks][cf], oacc[i][cf]);
            }
        __builtin_amdgcn_s_setprio(0);

        if (t < 15) {
            if (t < 14) asm volatile("s_waitcnt vmcnt(4)" ::: "memory");
            else        asm volatile("s_waitcnt vmcnt(0)" ::: "memory");
            __builtin_amdgcn_s_barrier();
        }
        cur = cur + 1; if (cur == 3) cur = 0;
    }

#pragma unroll
    for (int i = 0; i < 2; i++)
#pragma unroll
        for (int r = 0; r < 4; r++) {
            float inv = 1.0f / lacc[i][r];
            int n = q0 + wave * 32 + i * 16 + lg * 4 + r;
            size_t obase = ((size_t)b * 1024 + n) * 512 + h * 64;
#pragma unroll
            for (int cf = 0; cf < 4; cf++)
                aoT[obase + cf * 16 + l15] = f2bf(oacc[i][cf][r] * inv);
        }
}

// ---------------------------------------------------------------- proj GEMM + residual
// BK=32, quad-buffered ring, counted-vmcnt pipeline (3 loads/wave/tile ->
// vmcnt(6)). LDS 48KB -> 3 blocks/CU.
__global__ __launch_bounds__(256) void gemm_proj(const ushort* __restrict__ Wb,
                                                 const ushort* __restrict__ aoT,
                                                 const float* __restrict__ projb,
                                                 const float* __restrict__ x,
                                                 float* __restrict__ out) {
    int lane = threadIdx.x & 63, wave = threadIdx.x >> 6;
    int l15 = lane & 15, lg = lane >> 4;
    int bi = blockIdx.x;
    int b = bi & 7;
    int slot = bi >> 3;
    int m0 = (slot & 3) * 128;
    int n0 = (slot >> 2) * 64;
    int mw = (wave >> 1) * 64, nw = (wave & 1) * 32;
    const ushort* Ag = Wb + (size_t)m0 * 512;
    const ushort* Bg = aoT + (size_t)b * 524288 + (size_t)n0 * 512;

    __shared__ ushort abuf[4][4096];   // 128 x 32
    __shared__ ushort bbuf[4][2048];   // 64 x 32

    f32x4 acc[4][2] = {};
#pragma unroll
    for (int p = 0; p < 3; ++p) {
        stage_tile32(abuf[p], Ag + p * 32, 512, 8, wave, lane);
        stage_tile32(bbuf[p], Bg + p * 32, 512, 4, wave, lane);
    }
    asm volatile("s_waitcnt vmcnt(6)" ::: "memory");
    __builtin_amdgcn_s_barrier();

#pragma unroll 1
    for (int t = 0; t < 16; ++t) {
        if (t < 13) {
            int nxt = (t + 3) & 3;
            stage_tile32(abuf[nxt], Ag + (t + 3) * 32, 512, 8, wave, lane);
            stage_tile32(bbuf[nxt], Bg + (t + 3) * 32, 512, 4, wave, lane);
        }
        const ushort* A = abuf[t & 3];
        const ushort* B = bbuf[t & 3];
        bf16x8 af[4], bfr[2];
#pragma unroll
        for (int i = 0; i < 4; i++)
            af[i] = lds_read_row32(A, mw + i * 16 + l15, lg * 16);
#pragma unroll
        for (int j = 0; j < 2; j++)
            bfr[j] = lds_read_row32(B, nw + j * 16 + l15, lg * 16);
        __builtin_amdgcn_s_setprio(1);
#pragma unroll
        for (int i = 0; i < 4; i++)
#pragma unroll
            for (int j = 0; j < 2; j++)
                acc[i][j] = MFMA(af[i], bfr[j], acc[i][j]);
        __builtin_amdgcn_s_setprio(0);
        if (t < 15) {
            if (t < 13)      asm volatile("s_waitcnt vmcnt(6)" ::: "memory");
            else if (t == 13) asm volatile("s_waitcnt vmcnt(3)" ::: "memory");
            else              asm volatile("s_waitcnt vmcnt(0)" ::: "memory");
            __builtin_amdgcn_s_barrier();
        }
    }

#pragma unroll
    for (int i = 0; i < 4; i++) {
        int ob = m0 + mw + i * 16 + lg * 4;
        float bias[4];
#pragma unroll
        for (int r = 0; r < 4; r++) bias[r] = projb[ob + r];
#pragma unroll
        for (int j = 0; j < 2; j++) {
            int n = n0 + nw + j * 16 + l15;
#pragma unroll
            for (int r = 0; r < 4; r++) {
                size_t idx = (size_t)(b * 512 + ob + r) * 1024 + n;
                out[idx] = x[idx] + bias[r] + acc[i][j][r];
            }
        }
    }
}

// ---------------------------------------------------------------- launcher
extern "C" void kernel_launch(void* const* d_in, const int* in_sizes, int n_in,
                              void* d_out, int out_size, void* d_ws, size_t ws_size,
                              hipStream_t stream) {
    const float* x     = (const float*)d_in[0];
    const float* gnw   = (const float*)d_in[1];
    const float* gnb   = (const float*)d_in[2];
    const float* qkvw  = (const float*)d_in[3];
    const float* qkvb  = (const float*)d_in[4];
    const float* projw = (const float*)d_in[5];
    const float* projb = (const float*)d_in[6];
    float* out = (float*)d_out;

    char* ws = (char*)d_ws;
    ushort* hnT    = (ushort*)(ws);                          // 8 MB (reused as aoT)
    ushort* qT     = (ushort*)(ws + (size_t)(8u << 20));     // 8 MB
    ushort* kT     = (ushort*)(ws + (size_t)(16u << 20));    // 8 MB
    ushort* vbuf   = (ushort*)(ws + (size_t)(24u << 20));    // 8 MB
    ushort* qkvwb  = (ushort*)(ws + (size_t)(32u << 20));    // 1.5 MB
    ushort* projwb = (ushort*)(ws + (size_t)(32u << 20) + 1572864);  // 0.5 MB

    gn_cvt_kernel<<<dim3(1280), dim3(256), 0, stream>>>(x, gnw, gnb, hnT,
                                                        qkvw, projw, qkvwb, projwb);
    gemm_qkv<<<dim3(768), dim3(256), 0, stream>>>(qkvwb, hnT, qkvb, qT, kT, vbuf);
    attn_kernel<<<dim3(512), dim3(256), 0, stream>>>(qT, kT, vbuf, hnT /* aoT */);
    gemm_proj<<<dim3(512), dim3(256), 0, stream>>>(projwb, hnT, projb, x, out);
}

// Round 12
// 80.199 us; speedup vs baseline: 1.4806x; 1.0771x over previous
//
#include <hip/hip_runtime.h>

typedef __bf16 bf16x8 __attribute__((ext_vector_type(8)));
typedef float f32x4 __attribute__((ext_vector_type(4)));

#define MFMA(a, b, c) __builtin_amdgcn_mfma_f32_16x16x32_bf16(a, b, c, 0, 0, 0)

#define CS 0.18033688011112042f   /* 0.125 * log2(e) */

__device__ __forceinline__ ushort f2bf(float f) {
    __bf16 h = (__bf16)f;
    return *(ushort*)&h;
}
__device__ __forceinline__ float bf2f(ushort u) {
    unsigned int x = ((unsigned int)u) << 16;
    return __uint_as_float(x);
}

// ---- stage (8*nchunks)-row x 64-col bf16 tile into LDS, XOR-swizzled (128B rows)
__device__ __forceinline__ void stage_tile64(ushort* lds, const ushort* gbase,
                                             int row_stride, int nchunks,
                                             int wave, int lane) {
    int r8 = lane >> 3;
    int cswz = ((lane & 7) ^ r8) << 4;
#pragma unroll
    for (int c = wave; c < nchunks; c += 4) {
        const char* g = (const char*)(gbase + (size_t)(c * 8 + r8) * row_stride) + cswz;
        __builtin_amdgcn_global_load_lds(
            (const __attribute__((address_space(1))) unsigned int*)g,
            (__attribute__((address_space(3))) unsigned int*)((char*)lds + c * 1024),
            16, 0, 0);
    }
}

__device__ __forceinline__ bf16x8 lds_read_row(const ushort* lds, int row, int cb) {
    return *(const bf16x8*)((const char*)lds + row * 128 + (cb ^ ((row & 7) << 4)));
}

// ---- stage (16*nchunks)-row x 32-col bf16 tile into LDS, XOR-swizzled (64B rows)
__device__ __forceinline__ void stage_tile32(ushort* lds, const ushort* gbase,
                                             int row_stride, int nchunks,
                                             int wave, int lane) {
    int r16 = lane >> 2;
    int csw = (((lane & 3) ^ ((lane >> 3) & 3)) << 3);
#pragma unroll
    for (int c = wave; c < nchunks; c += 4) {
        const ushort* g = gbase + (size_t)(c * 16 + r16) * row_stride + csw;
        __builtin_amdgcn_global_load_lds(
            (const __attribute__((address_space(1))) unsigned int*)g,
            (__attribute__((address_space(3))) unsigned int*)((char*)lds + c * 1024),
            16, 0, 0);
    }
}

__device__ __forceinline__ bf16x8 lds_read_row32(const ushort* lds, int row, int cb) {
    return *(const bf16x8*)((const char*)lds + row * 64 + (cb ^ (((row >> 1) & 3) << 4)));
}

// ---------------------------------------------------------------- groupnorm (+fused weight cvt)
// blocks [0,256): GroupNorm per (b,g) -- x read ONCE from HBM: pass 1
// accumulates stats and caches the 16x1024 tile as bf16 in LDS (row pad 1028
// ushorts so pass-2 strided reads are <=2-way bank aliases = free); pass 2
// normalizes from LDS and writes coalesced ushort4 to hnT[b][n][c].
// blocks [256,1280): fp32->bf16 weight cvt.
__global__ __launch_bounds__(256) void gn_cvt_kernel(const float* __restrict__ x,
                                                     const float* __restrict__ gnw,
                                                     const float* __restrict__ gnb,
                                                     ushort* __restrict__ hnT,
                                                     const float* __restrict__ w1,
                                                     const float* __restrict__ w2,
                                                     ushort* __restrict__ o1,
                                                     ushort* __restrict__ o2) {
    __shared__ ushort xcache[16 * 1028];   // ~32.1 KB
    __shared__ float red[8];
    __shared__ float sw[16], sb[16];

    if (blockIdx.x >= 256) {
        int t = (blockIdx.x - 256) * 256 + threadIdx.x;
        const int n1q = (1536 * 512) / 4;
        float4 v;
        ushort* dst;
        int idx;
        if (t < n1q) {
            v = ((const float4*)w1)[t]; dst = o1; idx = t;
        } else {
            idx = t - n1q;
            v = ((const float4*)w2)[idx]; dst = o2;
        }
        ushort4 p;
        p.x = f2bf(v.x); p.y = f2bf(v.y); p.z = f2bf(v.z); p.w = f2bf(v.w);
        ((ushort4*)dst)[idx] = p;
        return;
    }

    int b = blockIdx.x >> 5, g = blockIdx.x & 31;
    const float* xp = x + (size_t)(b * 512 + g * 16) * 1024;
    int t = threadIdx.x;

    float s = 0.f, ss = 0.f;
    const float4* xp4 = (const float4*)xp;
    for (int i = t; i < 4096; i += 256) {
        float4 v = xp4[i];
        s += (v.x + v.y) + (v.z + v.w);
        ss += (v.x * v.x + v.y * v.y) + (v.z * v.z + v.w * v.w);
        int f = i * 4;
        int cc = f >> 10, nl = f & 1023;
        ushort4 c;
        c.x = f2bf(v.x); c.y = f2bf(v.y); c.z = f2bf(v.z); c.w = f2bf(v.w);
        *(ushort4*)&xcache[cc * 1028 + nl] = c;
    }
#pragma unroll
    for (int off = 32; off >= 1; off >>= 1) {
        s += __shfl_xor(s, off);
        ss += __shfl_xor(ss, off);
    }
    int wave = t >> 6;
    if ((t & 63) == 0) { red[wave] = s; red[wave + 4] = ss; }
    if (t < 16) { sw[t] = gnw[g * 16 + t]; sb[t] = gnb[g * 16 + t]; }
    __syncthreads();
    float S = red[0] + red[1] + red[2] + red[3];
    float SS = red[4] + red[5] + red[6] + red[7];
    float mean = S * (1.0f / 16384.0f);
    float var = SS * (1.0f / 16384.0f) - mean * mean;
    float rstd = rsqrtf(var + 1e-5f);

    // pass 2: normalize from LDS, write hnT[b][n][g*16 + cc0..cc0+3]
    int cc0 = (t & 3) * 4;
    int nb = t >> 2;
    float w0 = sw[cc0] * rstd, w1_ = sw[cc0 + 1] * rstd,
          w2_ = sw[cc0 + 2] * rstd, w3 = sw[cc0 + 3] * rstd;
    float b0 = sb[cc0] - mean * w0, b1 = sb[cc0 + 1] - mean * w1_,
          b2 = sb[cc0 + 2] - mean * w2_, b3 = sb[cc0 + 3] - mean * w3;
#pragma unroll
    for (int k = 0; k < 16; ++k) {
        int nl = nb + 64 * k;
        ushort4 p;
        p.x = f2bf(bf2f(xcache[(cc0 + 0) * 1028 + nl]) * w0 + b0);
        p.y = f2bf(bf2f(xcache[(cc0 + 1) * 1028 + nl]) * w1_ + b1);
        p.z = f2bf(bf2f(xcache[(cc0 + 2) * 1028 + nl]) * w2_ + b2);
        p.w = f2bf(bf2f(xcache[(cc0 + 3) * 1028 + nl]) * w3 + b3);
        *(ushort4*)(hnT + ((size_t)b * 1024 + nl) * 512 + g * 16 + cc0) = p;
    }
}

// ---------------------------------------------------------------- QKV GEMM
// BK=32, TRIPLE-buffered LDS ring (48KB -> 3 blocks/CU, matching grid 768),
// counted-vmcnt pipeline: stage t+2, wait vmcnt(4) (t+1 resident, t+2's 4
// loads in flight), raw barrier -- no drain in steady state.
// V written kv-permuted (pi^-1) for attention's in-register P; Q pre-scaled.
__global__ __launch_bounds__(256, 3) void gemm_qkv(const ushort* __restrict__ Wb,
                                                   const ushort* __restrict__ hnT,
                                                   const float* __restrict__ qkvb,
                                                   ushort* __restrict__ qT,
                                                   ushort* __restrict__ kT,
                                                   ushort* __restrict__ vb) {
    int lane = threadIdx.x & 63, wave = threadIdx.x >> 6;
    int l15 = lane & 15, lg = lane >> 4;
    int bi = blockIdx.x;
    int b = bi & 7;
    int slot = bi >> 3;
    int m0 = (slot % 12) * 128;
    int n0 = (slot / 12) * 128;
    int mw = (wave >> 1) * 64, nw = (wave & 1) * 64;
    const ushort* Ag = Wb + (size_t)m0 * 512;
    const ushort* Bg = hnT + (size_t)b * 524288 + (size_t)n0 * 512;

    __shared__ ushort abuf[3][4096];   // 128 x 32 each
    __shared__ ushort bbuf[3][4096];

    f32x4 acc[4][4] = {};
    // prologue: stage tiles 0,1 (4 loads/wave each)
#pragma unroll
    for (int p = 0; p < 2; ++p) {
        stage_tile32(abuf[p], Ag + p * 32, 512, 8, wave, lane);
        stage_tile32(bbuf[p], Bg + p * 32, 512, 8, wave, lane);
    }
    asm volatile("s_waitcnt vmcnt(4)" ::: "memory");   // tile 0 resident
    __builtin_amdgcn_s_barrier();

    int cur = 0;
#pragma unroll 1
    for (int t = 0; t < 16; ++t) {
        if (t < 14) {
            int nxt = cur + 2; if (nxt >= 3) nxt -= 3;
            stage_tile32(abuf[nxt], Ag + (t + 2) * 32, 512, 8, wave, lane);
            stage_tile32(bbuf[nxt], Bg + (t + 2) * 32, 512, 8, wave, lane);
        }
        const ushort* A = abuf[cur];
        const ushort* B = bbuf[cur];
        bf16x8 af[4], bfr[4];
#pragma unroll
        for (int i = 0; i < 4; i++)
            af[i] = lds_read_row32(A, mw + i * 16 + l15, lg * 16);
#pragma unroll
        for (int j = 0; j < 4; j++)
            bfr[j] = lds_read_row32(B, nw + j * 16 + l15, lg * 16);
        __builtin_amdgcn_s_setprio(1);
#pragma unroll
        for (int i = 0; i < 4; i++)
#pragma unroll
            for (int j = 0; j < 4; j++)
                acc[i][j] = MFMA(af[i], bfr[j], acc[i][j]);
        __builtin_amdgcn_s_setprio(0);
        if (t < 15) {
            if (t < 14) asm volatile("s_waitcnt vmcnt(4)" ::: "memory");
            else        asm volatile("s_waitcnt vmcnt(0)" ::: "memory");
            __builtin_amdgcn_s_barrier();
        }
        cur = cur + 1; if (cur == 3) cur = 0;
    }

#pragma unroll
    for (int i = 0; i < 4; i++) {
        int ob = m0 + mw + i * 16 + lg * 4;
        float bias[4];
#pragma unroll
        for (int r = 0; r < 4; r++) bias[r] = qkvb[ob + r];
        int part = ob >> 9;
        int oo = ob & 511;
#pragma unroll
        for (int j = 0; j < 4; j++) {
            int n = n0 + nw + j * 16 + l15;
            if (part == 2) {
                int L = n & 63;
                int cf = L >> 4;
                int s = ((cf >> 1) << 5) | (((L >> 2) & 3) << 3) | ((cf & 1) << 2) | (L & 3);
                int np = (n & ~63) | s;
#pragma unroll
                for (int r = 0; r < 4; r++)
                    vb[(size_t)(b * 512 + oo + r) * 1024 + np] = f2bf(acc[i][j][r] + bias[r]);
            } else {
                ushort* dst = part ? kT : qT;
                float sc = part ? 1.0f : CS;      // pre-scale Q by 0.125*log2(e)
                int h = oo >> 6, dd = oo & 63;
                ushort4 p;
                p.x = f2bf((acc[i][j][0] + bias[0]) * sc);
                p.y = f2bf((acc[i][j][1] + bias[1]) * sc);
                p.z = f2bf((acc[i][j][2] + bias[2]) * sc);
                p.w = f2bf((acc[i][j][3] + bias[3]) * sc);
                *(ushort4*)(dst + ((size_t)((b * 8 + h) * 1024 + n)) * 64 + dd) = p;
            }
        }
    }
}

// ---------------------------------------------------------------- attention
// 128 q-rows/block (4 waves x 32 rows). K/V triple-buffered, counted-vmcnt
// pipeline. Swapped QK^T keeps P in registers (V kv-permuted by pi^-1 in
// gemm_qkv). Q pre-scaled: P = exp2(S). Row sums via ones-MFMA.
__global__ __launch_bounds__(256) void attn_kernel(const ushort* __restrict__ qT,
                                                   const ushort* __restrict__ kT,
                                                   const ushort* __restrict__ vb,
                                                   ushort* __restrict__ aoT) {
    int bi = blockIdx.x;
    int bh = ((bi >> 6) << 3) | (bi & 7);
    int q0 = ((bi >> 3) & 7) * 128;
    int b = bh >> 3, h = bh & 7;
    int lane = threadIdx.x & 63, wave = threadIdx.x >> 6;
    int l15 = lane & 15, lg = lane >> 4;
    const ushort* qp = qT + (size_t)bh * 65536;
    const ushort* kp = kT + (size_t)bh * 65536;
    const ushort* vp = vb + (size_t)bh * 65536;

    __shared__ ushort kbuf[3][4096];   // [kv 64][d 64]
    __shared__ ushort vbuf[3][4096];   // [dd 64][kv-slot 64] (pi-permuted)

    bf16x8 vone;
#pragma unroll
    for (int e = 0; e < 8; e++) vone[e] = (__bf16)1.0f;

    bf16x8 qf[2][2];
#pragma unroll
    for (int i = 0; i < 2; i++)
#pragma unroll
        for (int kh = 0; kh < 2; kh++)
            qf[i][kh] = *(const bf16x8*)(qp + (size_t)(q0 + wave * 32 + i * 16 + l15) * 64 + kh * 32 + lg * 8);

    f32x4 oacc[2][4] = {};
    f32x4 lacc[2] = {};

    stage_tile64(kbuf[0], kp, 64, 8, wave, lane);
    stage_tile64(vbuf[0], vp, 1024, 8, wave, lane);
    stage_tile64(kbuf[1], kp + 4096, 64, 8, wave, lane);
    stage_tile64(vbuf[1], vp + 64, 1024, 8, wave, lane);
    asm volatile("s_waitcnt vmcnt(4)" ::: "memory");   // tile 0 resident
    __builtin_amdgcn_s_barrier();

    int cur = 0;
#pragma unroll 1
    for (int t = 0; t < 16; ++t) {
        if (t < 14) {
            int nxt = cur + 2; if (nxt >= 3) nxt -= 3;
            stage_tile64(kbuf[nxt], kp + (size_t)(t + 2) * 4096, 64, 8, wave, lane);
            stage_tile64(vbuf[nxt], vp + (t + 2) * 64, 1024, 8, wave, lane);
        }
        const ushort* kb = kbuf[cur];
        const ushort* vc = vbuf[cur];

        f32x4 sacc[2][4] = {};
        __builtin_amdgcn_s_setprio(1);
#pragma unroll
        for (int kh = 0; kh < 2; kh++)
#pragma unroll
            for (int cf = 0; cf < 4; cf++) {
                bf16x8 kf = lds_read_row(kb, cf * 16 + l15, kh * 64 + lg * 16);
                sacc[0][cf] = MFMA(kf, qf[0][kh], sacc[0][cf]);
                sacc[1][cf] = MFMA(kf, qf[1][kh], sacc[1][cf]);
            }
        __builtin_amdgcn_s_setprio(0);

        bf16x8 vf[2][4];
#pragma unroll
        for (int ks = 0; ks < 2; ks++)
#pragma unroll
            for (int cf = 0; cf < 4; cf++)
                vf[ks][cf] = lds_read_row(vc, cf * 16 + l15, ks * 64 + lg * 16);

        bf16x8 pa[2][2];
#pragma unroll
        for (int i = 0; i < 2; i++)
#pragma unroll
            for (int ks = 0; ks < 2; ks++) {
                bf16x8 tr;
#pragma unroll
                for (int jhi = 0; jhi < 2; jhi++)
#pragma unroll
                    for (int r = 0; r < 4; r++)
                        tr[jhi * 4 + r] = (__bf16)exp2f(sacc[i][ks * 2 + jhi][r]);
                pa[i][ks] = tr;
            }

        __builtin_amdgcn_s_setprio(1);
#pragma unroll
        for (int i = 0; i < 2; i++)
#pragma unroll
            for (int ks = 0; ks < 2; ks++) {
                lacc[i] = MFMA(pa[i][ks], vone, lacc[i]);   // row sums on matrix pipe
#pragma unroll
                for (int cf = 0; cf < 4; cf++)
                    oacc[i][cf] = MFMA(pa[i][ks], vf[ks][cf], oacc[i][cf]);
            }
        __builtin_amdgcn_s_setprio(0);

        if (t < 15) {
            if (t < 14) asm volatile("s_waitcnt vmcnt(4)" ::: "memory");
            else        asm volatile("s_waitcnt vmcnt(0)" ::: "memory");
            __builtin_amdgcn_s_barrier();
        }
        cur = cur + 1; if (cur == 3) cur = 0;
    }

#pragma unroll
    for (int i = 0; i < 2; i++)
#pragma unroll
        for (int r = 0; r < 4; r++) {
            float inv = 1.0f / lacc[i][r];
            int n = q0 + wave * 32 + i * 16 + lg * 4 + r;
            size_t obase = ((size_t)b * 1024 + n) * 512 + h * 64;
#pragma unroll
            for (int cf = 0; cf < 4; cf++)
                aoT[obase + cf * 16 + l15] = f2bf(oacc[i][cf][r] * inv);
        }
}

// ---------------------------------------------------------------- proj GEMM + residual
// BK=32, quad-buffered ring, counted-vmcnt pipeline (3 loads/wave/tile ->
// vmcnt(6)).
__global__ __launch_bounds__(256) void gemm_proj(const ushort* __restrict__ Wb,
                                                 const ushort* __restrict__ aoT,
                                                 const float* __restrict__ projb,
                                                 const float* __restrict__ x,
                                                 float* __restrict__ out) {
    int lane = threadIdx.x & 63, wave = threadIdx.x >> 6;
    int l15 = lane & 15, lg = lane >> 4;
    int bi = blockIdx.x;
    int b = bi & 7;
    int slot = bi >> 3;
    int m0 = (slot & 3) * 128;
    int n0 = (slot >> 2) * 64;
    int mw = (wave >> 1) * 64, nw = (wave & 1) * 32;
    const ushort* Ag = Wb + (size_t)m0 * 512;
    const ushort* Bg = aoT + (size_t)b * 524288 + (size_t)n0 * 512;

    __shared__ ushort abuf[4][4096];   // 128 x 32
    __shared__ ushort bbuf[4][2048];   // 64 x 32

    f32x4 acc[4][2] = {};
#pragma unroll
    for (int p = 0; p < 3; ++p) {
        stage_tile32(abuf[p], Ag + p * 32, 512, 8, wave, lane);
        stage_tile32(bbuf[p], Bg + p * 32, 512, 4, wave, lane);
    }
    asm volatile("s_waitcnt vmcnt(6)" ::: "memory");
    __builtin_amdgcn_s_barrier();

#pragma unroll 1
    for (int t = 0; t < 16; ++t) {
        if (t < 13) {
            int nxt = (t + 3) & 3;
            stage_tile32(abuf[nxt], Ag + (t + 3) * 32, 512, 8, wave, lane);
            stage_tile32(bbuf[nxt], Bg + (t + 3) * 32, 512, 4, wave, lane);
        }
        const ushort* A = abuf[t & 3];
        const ushort* B = bbuf[t & 3];
        bf16x8 af[4], bfr[2];
#pragma unroll
        for (int i = 0; i < 4; i++)
            af[i] = lds_read_row32(A, mw + i * 16 + l15, lg * 16);
#pragma unroll
        for (int j = 0; j < 2; j++)
            bfr[j] = lds_read_row32(B, nw + j * 16 + l15, lg * 16);
        __builtin_amdgcn_s_setprio(1);
#pragma unroll
        for (int i = 0; i < 4; i++)
#pragma unroll
            for (int j = 0; j < 2; j++)
                acc[i][j] = MFMA(af[i], bfr[j], acc[i][j]);
        __builtin_amdgcn_s_setprio(0);
        if (t < 15) {
            if (t < 13)      asm volatile("s_waitcnt vmcnt(6)" ::: "memory");
            else if (t == 13) asm volatile("s_waitcnt vmcnt(3)" ::: "memory");
            else              asm volatile("s_waitcnt vmcnt(0)" ::: "memory");
            __builtin_amdgcn_s_barrier();
        }
    }

#pragma unroll
    for (int i = 0; i < 4; i++) {
        int ob = m0 + mw + i * 16 + lg * 4;
        float bias[4];
#pragma unroll
        for (int r = 0; r < 4; r++) bias[r] = projb[ob + r];
#pragma unroll
        for (int j = 0; j < 2; j++) {
            int n = n0 + nw + j * 16 + l15;
#pragma unroll
            for (int r = 0; r < 4; r++) {
                size_t idx = (size_t)(b * 512 + ob + r) * 1024 + n;
                out[idx] = x[idx] + bias[r] + acc[i][j][r];
            }
        }
    }
}

// ---------------------------------------------------------------- launcher
extern "C" void kernel_launch(void* const* d_in, const int* in_sizes, int n_in,
                              void* d_out, int out_size, void* d_ws, size_t ws_size,
                              hipStream_t stream) {
    const float* x     = (const float*)d_in[0];
    const float* gnw   = (const float*)d_in[1];
    const float* gnb   = (const float*)d_in[2];
    const float* qkvw  = (const float*)d_in[3];
    const float* qkvb  = (const float*)d_in[4];
    const float* projw = (const float*)d_in[5];
    const float* projb = (const float*)d_in[6];
    float* out = (float*)d_out;

    char* ws = (char*)d_ws;
    ushort* hnT    = (ushort*)(ws);                          // 8 MB (reused as aoT)
    ushort* qT     = (ushort*)(ws + (size_t)(8u << 20));     // 8 MB
    ushort* kT     = (ushort*)(ws + (size_t)(16u << 20));    // 8 MB
    ushort* vbuf   = (ushort*)(ws + (size_t)(24u << 20));    // 8 MB
    ushort* qkvwb  = (ushort*)(ws + (size_t)(32u << 20));    // 1.5 MB
    ushort* projwb = (ushort*)(ws + (size_t)(32u << 20) + 1572864);  // 0.5 MB

    gn_cvt_kernel<<<dim3(1280), dim3(256), 0, stream>>>(x, gnw, gnb, hnT,
                                                        qkvw, projw, qkvwb, projwb);
    gemm_qkv<<<dim3(768), dim3(256), 0, stream>>>(qkvwb, hnT, qkvb, qT, kT, vbuf);
    attn_kernel<<<dim3(512), dim3(256), 0, stream>>>(qT, kT, vbuf, hnT /* aoT */);
    gemm_proj<<<dim3(512), dim3(256), 0, stream>>>(projwb, hnT, projb, x, out);
}

// Round 13
// 79.774 us; speedup vs baseline: 1.4885x; 1.0053x over previous
//
#include <hip/hip_runtime.h>

typedef __bf16 bf16x8 __attribute__((ext_vector_type(8)));
typedef float f32x4 __attribute__((ext_vector_type(4)));

#define MFMA(a, b, c) __builtin_amdgcn_mfma_f32_16x16x32_bf16(a, b, c, 0, 0, 0)

#define CS 0.18033688011112042f   /* 0.125 * log2(e) */

__device__ __forceinline__ ushort f2bf(float f) {
    __bf16 h = (__bf16)f;
    return *(ushort*)&h;
}
__device__ __forceinline__ float bf2f(ushort u) {
    unsigned int x = ((unsigned int)u) << 16;
    return __uint_as_float(x);
}

// ---- stage (8*nchunks)-row x 64-col bf16 tile into LDS, XOR-swizzled (128B rows)
__device__ __forceinline__ void stage_tile64(ushort* lds, const ushort* gbase,
                                             int row_stride, int nchunks,
                                             int wave, int lane) {
    int r8 = lane >> 3;
    int cswz = ((lane & 7) ^ r8) << 4;
#pragma unroll
    for (int c = wave; c < nchunks; c += 4) {
        const char* g = (const char*)(gbase + (size_t)(c * 8 + r8) * row_stride) + cswz;
        __builtin_amdgcn_global_load_lds(
            (const __attribute__((address_space(1))) unsigned int*)g,
            (__attribute__((address_space(3))) unsigned int*)((char*)lds + c * 1024),
            16, 0, 0);
    }
}

__device__ __forceinline__ bf16x8 lds_read_row(const ushort* lds, int row, int cb) {
    return *(const bf16x8*)((const char*)lds + row * 128 + (cb ^ ((row & 7) << 4)));
}

// ---- stage (16*nchunks)-row x 32-col bf16 tile into LDS, XOR-swizzled (64B rows)
__device__ __forceinline__ void stage_tile32(ushort* lds, const ushort* gbase,
                                             int row_stride, int nchunks,
                                             int wave, int lane) {
    int r16 = lane >> 2;
    int csw = (((lane & 3) ^ ((lane >> 3) & 3)) << 3);
#pragma unroll
    for (int c = wave; c < nchunks; c += 4) {
        const ushort* g = gbase + (size_t)(c * 16 + r16) * row_stride + csw;
        __builtin_amdgcn_global_load_lds(
            (const __attribute__((address_space(1))) unsigned int*)g,
            (__attribute__((address_space(3))) unsigned int*)((char*)lds + c * 1024),
            16, 0, 0);
    }
}

__device__ __forceinline__ bf16x8 lds_read_row32(const ushort* lds, int row, int cb) {
    return *(const bf16x8*)((const char*)lds + row * 64 + (cb ^ (((row >> 1) & 3) << 4)));
}

// ---------------------------------------------------------------- groupnorm (+fused weight cvt)
// blocks [0,256): GroupNorm per (b,g) -- x read ONCE from HBM (stats + bf16
// tile cache in LDS in pass 1; normalize from LDS in pass 2).
// blocks [256,1280): fp32->bf16 weight cvt.
__global__ __launch_bounds__(256) void gn_cvt_kernel(const float* __restrict__ x,
                                                     const float* __restrict__ gnw,
                                                     const float* __restrict__ gnb,
                                                     ushort* __restrict__ hnT,
                                                     const float* __restrict__ w1,
                                                     const float* __restrict__ w2,
                                                     ushort* __restrict__ o1,
                                                     ushort* __restrict__ o2) {
    __shared__ ushort xcache[16 * 1028];   // ~32.1 KB
    __shared__ float red[8];
    __shared__ float sw[16], sb[16];

    if (blockIdx.x >= 256) {
        int t = (blockIdx.x - 256) * 256 + threadIdx.x;
        const int n1q = (1536 * 512) / 4;
        float4 v;
        ushort* dst;
        int idx;
        if (t < n1q) {
            v = ((const float4*)w1)[t]; dst = o1; idx = t;
        } else {
            idx = t - n1q;
            v = ((const float4*)w2)[idx]; dst = o2;
        }
        ushort4 p;
        p.x = f2bf(v.x); p.y = f2bf(v.y); p.z = f2bf(v.z); p.w = f2bf(v.w);
        ((ushort4*)dst)[idx] = p;
        return;
    }

    int b = blockIdx.x >> 5, g = blockIdx.x & 31;
    const float* xp = x + (size_t)(b * 512 + g * 16) * 1024;
    int t = threadIdx.x;

    float s = 0.f, ss = 0.f;
    const float4* xp4 = (const float4*)xp;
    for (int i = t; i < 4096; i += 256) {
        float4 v = xp4[i];
        s += (v.x + v.y) + (v.z + v.w);
        ss += (v.x * v.x + v.y * v.y) + (v.z * v.z + v.w * v.w);
        int f = i * 4;
        int cc = f >> 10, nl = f & 1023;
        ushort4 c;
        c.x = f2bf(v.x); c.y = f2bf(v.y); c.z = f2bf(v.z); c.w = f2bf(v.w);
        *(ushort4*)&xcache[cc * 1028 + nl] = c;
    }
#pragma unroll
    for (int off = 32; off >= 1; off >>= 1) {
        s += __shfl_xor(s, off);
        ss += __shfl_xor(ss, off);
    }
    int wave = t >> 6;
    if ((t & 63) == 0) { red[wave] = s; red[wave + 4] = ss; }
    if (t < 16) { sw[t] = gnw[g * 16 + t]; sb[t] = gnb[g * 16 + t]; }
    __syncthreads();
    float S = red[0] + red[1] + red[2] + red[3];
    float SS = red[4] + red[5] + red[6] + red[7];
    float mean = S * (1.0f / 16384.0f);
    float var = SS * (1.0f / 16384.0f) - mean * mean;
    float rstd = rsqrtf(var + 1e-5f);

    int cc0 = (t & 3) * 4;
    int nb = t >> 2;
    float w0 = sw[cc0] * rstd, w1_ = sw[cc0 + 1] * rstd,
          w2_ = sw[cc0 + 2] * rstd, w3 = sw[cc0 + 3] * rstd;
    float b0 = sb[cc0] - mean * w0, b1 = sb[cc0 + 1] - mean * w1_,
          b2 = sb[cc0 + 2] - mean * w2_, b3 = sb[cc0 + 3] - mean * w3;
#pragma unroll
    for (int k = 0; k < 16; ++k) {
        int nl = nb + 64 * k;
        ushort4 p;
        p.x = f2bf(bf2f(xcache[(cc0 + 0) * 1028 + nl]) * w0 + b0);
        p.y = f2bf(bf2f(xcache[(cc0 + 1) * 1028 + nl]) * w1_ + b1);
        p.z = f2bf(bf2f(xcache[(cc0 + 2) * 1028 + nl]) * w2_ + b2);
        p.w = f2bf(bf2f(xcache[(cc0 + 3) * 1028 + nl]) * w3 + b3);
        *(ushort4*)(hnT + ((size_t)b * 1024 + nl) * 512 + g * 16 + cc0) = p;
    }
}

// ---------------------------------------------------------------- QKV GEMM
// BK=32, triple-buffered ring (48KB -> 3 blocks/CU), counted-vmcnt pipeline.
// V written kv-permuted (pi^-1) for attention's in-register P; Q pre-scaled.
__global__ __launch_bounds__(256, 3) void gemm_qkv(const ushort* __restrict__ Wb,
                                                   const ushort* __restrict__ hnT,
                                                   const float* __restrict__ qkvb,
                                                   ushort* __restrict__ qT,
                                                   ushort* __restrict__ kT,
                                                   ushort* __restrict__ vb) {
    int lane = threadIdx.x & 63, wave = threadIdx.x >> 6;
    int l15 = lane & 15, lg = lane >> 4;
    int bi = blockIdx.x;
    int b = bi & 7;
    int slot = bi >> 3;
    int m0 = (slot % 12) * 128;
    int n0 = (slot / 12) * 128;
    int mw = (wave >> 1) * 64, nw = (wave & 1) * 64;
    const ushort* Ag = Wb + (size_t)m0 * 512;
    const ushort* Bg = hnT + (size_t)b * 524288 + (size_t)n0 * 512;

    __shared__ ushort abuf[3][4096];
    __shared__ ushort bbuf[3][4096];

    f32x4 acc[4][4] = {};
#pragma unroll
    for (int p = 0; p < 2; ++p) {
        stage_tile32(abuf[p], Ag + p * 32, 512, 8, wave, lane);
        stage_tile32(bbuf[p], Bg + p * 32, 512, 8, wave, lane);
    }
    asm volatile("s_waitcnt vmcnt(4)" ::: "memory");
    __builtin_amdgcn_s_barrier();

    int cur = 0;
#pragma unroll 1
    for (int t = 0; t < 16; ++t) {
        if (t < 14) {
            int nxt = cur + 2; if (nxt >= 3) nxt -= 3;
            stage_tile32(abuf[nxt], Ag + (t + 2) * 32, 512, 8, wave, lane);
            stage_tile32(bbuf[nxt], Bg + (t + 2) * 32, 512, 8, wave, lane);
        }
        const ushort* A = abuf[cur];
        const ushort* B = bbuf[cur];
        bf16x8 af[4], bfr[4];
#pragma unroll
        for (int i = 0; i < 4; i++)
            af[i] = lds_read_row32(A, mw + i * 16 + l15, lg * 16);
#pragma unroll
        for (int j = 0; j < 4; j++)
            bfr[j] = lds_read_row32(B, nw + j * 16 + l15, lg * 16);
        __builtin_amdgcn_s_setprio(1);
#pragma unroll
        for (int i = 0; i < 4; i++)
#pragma unroll
            for (int j = 0; j < 4; j++)
                acc[i][j] = MFMA(af[i], bfr[j], acc[i][j]);
        __builtin_amdgcn_s_setprio(0);
        if (t < 15) {
            if (t < 14) asm volatile("s_waitcnt vmcnt(4)" ::: "memory");
            else        asm volatile("s_waitcnt vmcnt(0)" ::: "memory");
            __builtin_amdgcn_s_barrier();
        }
        cur = cur + 1; if (cur == 3) cur = 0;
    }

#pragma unroll
    for (int i = 0; i < 4; i++) {
        int ob = m0 + mw + i * 16 + lg * 4;
        float bias[4];
#pragma unroll
        for (int r = 0; r < 4; r++) bias[r] = qkvb[ob + r];
        int part = ob >> 9;
        int oo = ob & 511;
#pragma unroll
        for (int j = 0; j < 4; j++) {
            int n = n0 + nw + j * 16 + l15;
            if (part == 2) {
                int L = n & 63;
                int cf = L >> 4;
                int s = ((cf >> 1) << 5) | (((L >> 2) & 3) << 3) | ((cf & 1) << 2) | (L & 3);
                int np = (n & ~63) | s;
#pragma unroll
                for (int r = 0; r < 4; r++)
                    vb[(size_t)(b * 512 + oo + r) * 1024 + np] = f2bf(acc[i][j][r] + bias[r]);
            } else {
                ushort* dst = part ? kT : qT;
                float sc = part ? 1.0f : CS;
                int h = oo >> 6, dd = oo & 63;
                ushort4 p;
                p.x = f2bf((acc[i][j][0] + bias[0]) * sc);
                p.y = f2bf((acc[i][j][1] + bias[1]) * sc);
                p.z = f2bf((acc[i][j][2] + bias[2]) * sc);
                p.w = f2bf((acc[i][j][3] + bias[3]) * sc);
                *(ushort4*)(dst + ((size_t)((b * 8 + h) * 1024 + n)) * 64 + dd) = p;
            }
        }
    }
}

// ---------------------------------------------------------------- attention
// 128 q-rows/block (4 waves x 32 rows). K/V on a 4-buffer ring, TWO kv-tiles
// per barrier group: stage group g+1 (8 loads/wave) at group top, compute
// both tiles back-to-back, vmcnt(0)+barrier once per group (7 barriers vs 15;
// prefetch cover = full 2-tile compute). Swapped QK^T keeps P in registers
// (V kv-permuted by pi^-1 in gemm_qkv). Q pre-scaled: P = exp2(S). Row sums
// via ones-MFMA.
__global__ __launch_bounds__(256) void attn_kernel(const ushort* __restrict__ qT,
                                                   const ushort* __restrict__ kT,
                                                   const ushort* __restrict__ vb,
                                                   ushort* __restrict__ aoT) {
    int bi = blockIdx.x;
    int bh = ((bi >> 6) << 3) | (bi & 7);
    int q0 = ((bi >> 3) & 7) * 128;
    int b = bh >> 3, h = bh & 7;
    int lane = threadIdx.x & 63, wave = threadIdx.x >> 6;
    int l15 = lane & 15, lg = lane >> 4;
    const ushort* qp = qT + (size_t)bh * 65536;
    const ushort* kp = kT + (size_t)bh * 65536;
    const ushort* vp = vb + (size_t)bh * 65536;

    __shared__ ushort kbuf[4][4096];   // [kv 64][d 64]
    __shared__ ushort vbuf[4][4096];   // [dd 64][kv-slot 64] (pi-permuted)

    bf16x8 vone;
#pragma unroll
    for (int e = 0; e < 8; e++) vone[e] = (__bf16)1.0f;

    bf16x8 qf[2][2];
#pragma unroll
    for (int i = 0; i < 2; i++)
#pragma unroll
        for (int kh = 0; kh < 2; kh++)
            qf[i][kh] = *(const bf16x8*)(qp + (size_t)(q0 + wave * 32 + i * 16 + l15) * 64 + kh * 32 + lg * 8);

    f32x4 oacc[2][4] = {};
    f32x4 lacc[2] = {};

    // prologue: stage group 0 (tiles 0,1)
    stage_tile64(kbuf[0], kp, 64, 8, wave, lane);
    stage_tile64(vbuf[0], vp, 1024, 8, wave, lane);
    stage_tile64(kbuf[1], kp + 4096, 64, 8, wave, lane);
    stage_tile64(vbuf[1], vp + 64, 1024, 8, wave, lane);
    asm volatile("s_waitcnt vmcnt(0)" ::: "memory");
    __builtin_amdgcn_s_barrier();

#pragma unroll 1
    for (int g = 0; g < 8; ++g) {
        int t0 = 2 * g;
        if (g < 7) {
            int na = (t0 + 2) & 3, nb2 = (t0 + 3) & 3;
            stage_tile64(kbuf[na], kp + (size_t)(t0 + 2) * 4096, 64, 8, wave, lane);
            stage_tile64(vbuf[na], vp + (t0 + 2) * 64, 1024, 8, wave, lane);
            stage_tile64(kbuf[nb2], kp + (size_t)(t0 + 3) * 4096, 64, 8, wave, lane);
            stage_tile64(vbuf[nb2], vp + (t0 + 3) * 64, 1024, 8, wave, lane);
        }
#pragma unroll
        for (int u = 0; u < 2; ++u) {
            int t = t0 + u;
            const ushort* kb = kbuf[t & 3];
            const ushort* vc = vbuf[t & 3];

            f32x4 sacc[2][4] = {};
            __builtin_amdgcn_s_setprio(1);
#pragma unroll
            for (int kh = 0; kh < 2; kh++)
#pragma unroll
                for (int cf = 0; cf < 4; cf++) {
                    bf16x8 kf = lds_read_row(kb, cf * 16 + l15, kh * 64 + lg * 16);
                    sacc[0][cf] = MFMA(kf, qf[0][kh], sacc[0][cf]);
                    sacc[1][cf] = MFMA(kf, qf[1][kh], sacc[1][cf]);
                }
            __builtin_amdgcn_s_setprio(0);

            bf16x8 vf[2][4];
#pragma unroll
            for (int ks = 0; ks < 2; ks++)
#pragma unroll
                for (int cf = 0; cf < 4; cf++)
                    vf[ks][cf] = lds_read_row(vc, cf * 16 + l15, ks * 64 + lg * 16);

            bf16x8 pa[2][2];
#pragma unroll
            for (int i = 0; i < 2; i++)
#pragma unroll
                for (int ks = 0; ks < 2; ks++) {
                    bf16x8 tr;
#pragma unroll
                    for (int jhi = 0; jhi < 2; jhi++)
#pragma unroll
                        for (int r = 0; r < 4; r++)
                            tr[jhi * 4 + r] = (__bf16)exp2f(sacc[i][ks * 2 + jhi][r]);
                    pa[i][ks] = tr;
                }

            __builtin_amdgcn_s_setprio(1);
#pragma unroll
            for (int i = 0; i < 2; i++)
#pragma unroll
                for (int ks = 0; ks < 2; ks++) {
                    lacc[i] = MFMA(pa[i][ks], vone, lacc[i]);
#pragma unroll
                    for (int cf = 0; cf < 4; cf++)
                        oacc[i][cf] = MFMA(pa[i][ks], vf[ks][cf], oacc[i][cf]);
                }
            __builtin_amdgcn_s_setprio(0);
        }
        if (g < 7) {
            asm volatile("s_waitcnt vmcnt(0)" ::: "memory");
            __builtin_amdgcn_s_barrier();
        }
    }

#pragma unroll
    for (int i = 0; i < 2; i++)
#pragma unroll
        for (int r = 0; r < 4; r++) {
            float inv = 1.0f / lacc[i][r];
            int n = q0 + wave * 32 + i * 16 + lg * 4 + r;
            size_t obase = ((size_t)b * 1024 + n) * 512 + h * 64;
#pragma unroll
            for (int cf = 0; cf < 4; cf++)
                aoT[obase + cf * 16 + l15] = f2bf(oacc[i][cf][r] * inv);
        }
}

// ---------------------------------------------------------------- proj GEMM + residual
__global__ __launch_bounds__(256) void gemm_proj(const ushort* __restrict__ Wb,
                                                 const ushort* __restrict__ aoT,
                                                 const float* __restrict__ projb,
                                                 const float* __restrict__ x,
                                                 float* __restrict__ out) {
    int lane = threadIdx.x & 63, wave = threadIdx.x >> 6;
    int l15 = lane & 15, lg = lane >> 4;
    int bi = blockIdx.x;
    int b = bi & 7;
    int slot = bi >> 3;
    int m0 = (slot & 3) * 128;
    int n0 = (slot >> 2) * 64;
    int mw = (wave >> 1) * 64, nw = (wave & 1) * 32;
    const ushort* Ag = Wb + (size_t)m0 * 512;
    const ushort* Bg = aoT + (size_t)b * 524288 + (size_t)n0 * 512;

    __shared__ ushort abuf[4][4096];
    __shared__ ushort bbuf[4][2048];

    f32x4 acc[4][2] = {};
#pragma unroll
    for (int p = 0; p < 3; ++p) {
        stage_tile32(abuf[p], Ag + p * 32, 512, 8, wave, lane);
        stage_tile32(bbuf[p], Bg + p * 32, 512, 4, wave, lane);
    }
    asm volatile("s_waitcnt vmcnt(6)" ::: "memory");
    __builtin_amdgcn_s_barrier();

#pragma unroll 1
    for (int t = 0; t < 16; ++t) {
        if (t < 13) {
            int nxt = (t + 3) & 3;
            stage_tile32(abuf[nxt], Ag + (t + 3) * 32, 512, 8, wave, lane);
            stage_tile32(bbuf[nxt], Bg + (t + 3) * 32, 512, 4, wave, lane);
        }
        const ushort* A = abuf[t & 3];
        const ushort* B = bbuf[t & 3];
        bf16x8 af[4], bfr[2];
#pragma unroll
        for (int i = 0; i < 4; i++)
            af[i] = lds_read_row32(A, mw + i * 16 + l15, lg * 16);
#pragma unroll
        for (int j = 0; j < 2; j++)
            bfr[j] = lds_read_row32(B, nw + j * 16 + l15, lg * 16);
        __builtin_amdgcn_s_setprio(1);
#pragma unroll
        for (int i = 0; i < 4; i++)
#pragma unroll
            for (int j = 0; j < 2; j++)
                acc[i][j] = MFMA(af[i], bfr[j], acc[i][j]);
        __builtin_amdgcn_s_setprio(0);
        if (t < 15) {
            if (t < 13)      asm volatile("s_waitcnt vmcnt(6)" ::: "memory");
            else if (t == 13) asm volatile("s_waitcnt vmcnt(3)" ::: "memory");
            else              asm volatile("s_waitcnt vmcnt(0)" ::: "memory");
            __builtin_amdgcn_s_barrier();
        }
    }

#pragma unroll
    for (int i = 0; i < 4; i++) {
        int ob = m0 + mw + i * 16 + lg * 4;
        float bias[4];
#pragma unroll
        for (int r = 0; r < 4; r++) bias[r] = projb[ob + r];
#pragma unroll
        for (int j = 0; j < 2; j++) {
            int n = n0 + nw + j * 16 + l15;
#pragma unroll
            for (int r = 0; r < 4; r++) {
                size_t idx = (size_t)(b * 512 + ob + r) * 1024 + n;
                out[idx] = x[idx] + bias[r] + acc[i][j][r];
            }
        }
    }
}

// ---------------------------------------------------------------- launcher
extern "C" void kernel_launch(void* const* d_in, const int* in_sizes, int n_in,
                              void* d_out, int out_size, void* d_ws, size_t ws_size,
                              hipStream_t stream) {
    const float* x     = (const float*)d_in[0];
    const float* gnw   = (const float*)d_in[1];
    const float* gnb   = (const float*)d_in[2];
    const float* qkvw  = (const float*)d_in[3];
    const float* qkvb  = (const float*)d_in[4];
    const float* projw = (const float*)d_in[5];
    const float* projb = (const float*)d_in[6];
    float* out = (float*)d_out;

    char* ws = (char*)d_ws;
    ushort* hnT    = (ushort*)(ws);                          // 8 MB (reused as aoT)
    ushort* qT     = (ushort*)(ws + (size_t)(8u << 20));     // 8 MB
    ushort* kT     = (ushort*)(ws + (size_t)(16u << 20));    // 8 MB
    ushort* vbuf   = (ushort*)(ws + (size_t)(24u << 20));    // 8 MB
    ushort* qkvwb  = (ushort*)(ws + (size_t)(32u << 20));    // 1.5 MB
    ushort* projwb = (ushort*)(ws + (size_t)(32u << 20) + 1572864);  // 0.5 MB

    gn_cvt_kernel<<<dim3(1280), dim3(256), 0, stream>>>(x, gnw, gnb, hnT,
                                                        qkvw, projw, qkvwb, projwb);
    gemm_qkv<<<dim3(768), dim3(256), 0, stream>>>(qkvwb, hnT, qkvb, qT, kT, vbuf);
    attn_kernel<<<dim3(512), dim3(256), 0, stream>>>(qT, kT, vbuf, hnT /* aoT */);
    gemm_proj<<<dim3(512), dim3(256), 0, stream>>>(projwb, hnT, projb, x, out);
}